// Round 1
// 2607.192 us; speedup vs baseline: 5.8792x; 5.8792x over previous
//
#include <hip/hip_runtime.h>
#include <hip/hip_bf16.h>
#include <math.h>

typedef __hip_bfloat16 bf16;
#define DEV __device__ __forceinline__

DEV float tofl(float v){ return v; }
DEV float tofl(bf16 v){ return __bfloat162float(v); }
DEV bf16  f2b(float v){ return __float2bfloat16(v); }
DEV void  stout(float* p, float v){ *p = v; }
DEV void  stout(bf16*  p, float v){ *p = f2b(v); }

static constexpr int Cc=256, Nn=4096, Mm=32;
static constexpr size_t ACT = (size_t)8*Cc*Nn;   // elems per output tensor
static constexpr float EPSc = 1e-6f;

enum { EPI_NONE=0, EPI_SOFTPLUS=1 };

// ============================================================================
// 16-way register-blocked MAC over K=256 input channels.
// Weight addresses depend ONLY on block-uniform values + unrolled constants
// -> uniformity analysis scalarizes them (s_load), inner loop = 1 vload + 16 fma.
// Accumulation order over k is ascending (same as previous version).
// ============================================================================
template<typename TIN>
DEV void mac16(const TIN* __restrict__ inb, const float* __restrict__ wb,
               int WS, float* __restrict__ acc)
{
  for (int k=0;k<256;k+=4){
    float a0 = tofl(inb[(size_t)(k+0)<<12]);
    float a1 = tofl(inb[(size_t)(k+1)<<12]);
    float a2 = tofl(inb[(size_t)(k+2)<<12]);
    float a3 = tofl(inb[(size_t)(k+3)<<12]);
#pragma unroll
    for (int oo=0;oo<16;oo++){
      const float* wr = wb + (size_t)oo*WS + k;
      acc[oo] = fmaf(a3,wr[3],fmaf(a2,wr[2],fmaf(a1,wr[1],fmaf(a0,wr[0],acc[oo]))));
    }
  }
}

// ---- 1x1 conv, 16 out-channels per block: grid (N/256, O/16, B)
template<int EPI, typename TIN, typename TOUT>
__global__ __launch_bounds__(256) void c1_tile(const TIN* __restrict__ in,
    const float* __restrict__ w, TOUT* __restrict__ out, int O)
{
  int n  = blockIdx.x*256 + threadIdx.x;
  int o0 = blockIdx.y*16;
  int b  = blockIdx.z;
  const TIN* inb = in + (((size_t)b*256)<<12) + n;
  float acc[16] = {};
  mac16(inb, w + (size_t)o0*256, 256, acc);
#pragma unroll
  for (int oo=0;oo<16;oo++){
    float a = acc[oo];
    if (EPI==EPI_SOFTPLUS) a = fmaxf(a,0.f) + log1pf(expf(-fabsf(a)));
    stout(&out[(((size_t)b*O + o0 + oo)<<12) + n], a);
  }
}

// ---- fc1: relu6((px@W1 + b1)*s1 + t1) -> fp32 hid chunk (256 outs)
__global__ __launch_bounds__(256) void fc1_tile(const bf16* __restrict__ px,
    const float* __restrict__ w, float* __restrict__ hid,
    const float* __restrict__ bia, const float* __restrict__ s1,
    const float* __restrict__ t1)
{
  int n  = blockIdx.x*256 + threadIdx.x;
  int o0 = blockIdx.y*16;
  int b  = blockIdx.z;
  const bf16* inb = px + (((size_t)b*256)<<12) + n;
  float acc[16] = {};
  mac16(inb, w + (size_t)o0*256, 256, acc);
#pragma unroll
  for (int oo=0;oo<16;oo++){
    int o = o0+oo;
    float a = (acc[oo] + bia[o])*s1[o] + t1[o];
    hid[(((size_t)b*256 + o)<<12) + n] = fminf(fmaxf(a,0.f),6.f);
  }
}

// ---- fc2 K-chunk accumulate: weight row stride 1024
template<int INIT>
__global__ __launch_bounds__(256) void fc2_tile(const float* __restrict__ hid,
    const float* __restrict__ w, float* __restrict__ accb)
{
  int n  = blockIdx.x*256 + threadIdx.x;
  int o0 = blockIdx.y*16;
  int b  = blockIdx.z;
  const float* inb = hid + (((size_t)b*256)<<12) + n;
  float acc[16] = {};
  mac16(inb, w + (size_t)o0*1024, 1024, acc);
#pragma unroll
  for (int oo=0;oo<16;oo++){
    size_t idx = (((size_t)b*256 + o0 + oo)<<12) + n;
    if (INIT) accb[idx] = acc[oo]; else accb[idx] += acc[oo];
  }
}

// ---- fused CAttention(att.z) + KAttention epilogue + norm + bf16 px write.
// att is per-batch weights (b*65536); same mac16 structure.
__global__ __launch_bounds__(256) void catt_tile(const float* __restrict__ z1,
    const float* __restrict__ other, const float* __restrict__ Qf,
    const float* __restrict__ KVf, const float* __restrict__ invb,
    const float* __restrict__ att, const float* __restrict__ gkp,
    const float* __restrict__ gcp, const float* __restrict__ ns,
    const float* __restrict__ nt, bf16* __restrict__ px)
{
  int n  = blockIdx.x*256 + threadIdx.x;
  int o0 = blockIdx.y*16;
  int b  = blockIdx.z;
  const float* zb = z1 + (((size_t)b*256)<<12) + n;
  float acc[16] = {};
  mac16(zb, att + ((size_t)b<<16) + (size_t)o0*256, 256, acc);   // sum_d att[c,d]*z[d,n]
  // s2[c] = sum_m Q[m,n]*KV[m,c]   (KV reads are block-uniform -> scalar)
  const float* qb  = Qf + (((size_t)b*Mm)<<12) + n;
  const float* kvb = KVf + ((size_t)b<<13) + o0;
  float s2[16] = {};
#pragma unroll
  for (int m=0;m<Mm;m++){
    float qm = qb[(size_t)m<<12];
#pragma unroll
    for (int oo=0;oo<16;oo++) s2[oo] = fmaf(qm, kvb[m*256 + oo], s2[oo]);
  }
  float invv = invb[((size_t)b<<12)+n];
  float gk = gkp[0], gc = gcp[0];
#pragma unroll
  for (int oo=0;oo<16;oo++){
    int c = o0+oo;
    size_t idx = (((size_t)b*256 + c)<<12) + n;
    float a = 2.f*zb[(size_t)c<<12] + gc*acc[oo] + gk*s2[oo]*invv;
    px[idx] = f2b(other[idx]*a*ns[c] + nt[c]);
  }
}

// ============================================================================
// LDS-tiled SYRK-style row-dot GEMMs (reduction over the contiguous n axis).
// XOR swizzle: logical float4 col j of row r stored at phys col j^((r>>2)&7)
// -> row-strided ds_read_b128 lands <=2-way (free), broadcasts stay clean.
// K split 4-way into partial buffers (deterministic, no atomics).
// ============================================================================
DEV int swz(int r, int j){ return r*128 + ((j ^ ((r>>2)&7))<<2); }

// energy partials: Cp[ks][b][256][256]; 64x64 tile, 4x4 per thread.
// grid (16 tiles, 4 ksplit, 8 b)
__global__ __launch_bounds__(256) void syrk64(const float* __restrict__ Z,
    float* __restrict__ Cp)
{
  int ct = blockIdx.x >> 2, dt = blockIdx.x & 3;
  int ks = blockIdx.y, b = blockIdx.z;
  __shared__ __align__(16) float sa[64*128];
  __shared__ __align__(16) float sb[64*128];
  int tx = threadIdx.x & 15, ty = threadIdx.x >> 4;
  const float* Ab = Z + (((size_t)b*256 + ct*64)<<12);
  const float* Bb = Z + (((size_t)b*256 + dt*64)<<12);
  float acc[4][4] = {};
  for (int k0 = ks<<10; k0 < (ks<<10)+1024; k0 += 128){
    __syncthreads();
#pragma unroll
    for (int i=0;i<8;i++){
      int fi = threadIdx.x + i*256;
      int r = fi >> 5, j = fi & 31;
      *(float4*)&sa[swz(r,j)] = *(const float4*)&Ab[((size_t)r<<12) + k0 + (j<<2)];
      *(float4*)&sb[swz(r,j)] = *(const float4*)&Bb[((size_t)r<<12) + k0 + (j<<2)];
    }
    __syncthreads();
#pragma unroll 2
    for (int jj=0;jj<32;jj++){
      float4 av[4], bv[4];
#pragma unroll
      for (int i=0;i<4;i++) av[i] = *(const float4*)&sa[swz(4*ty+i,jj)];
#pragma unroll
      for (int i=0;i<4;i++) bv[i] = *(const float4*)&sb[swz(4*tx+i,jj)];
#pragma unroll
      for (int i=0;i<4;i++)
#pragma unroll
        for (int j2=0;j2<4;j2++)
          acc[i][j2] = fmaf(av[i].w,bv[j2].w, fmaf(av[i].z,bv[j2].z,
                       fmaf(av[i].y,bv[j2].y, fmaf(av[i].x,bv[j2].x, acc[i][j2]))));
    }
  }
  float* Cb = Cp + ((size_t)ks*8 + b)*65536;
#pragma unroll
  for (int i=0;i<4;i++)
#pragma unroll
    for (int j2=0;j2<4;j2++)
      Cb[(size_t)(ct*64 + 4*ty + i)*256 + dt*64 + 4*tx + j2] = acc[i][j2];
}

// KV partials: Cp[ks][b][32][256]; 32x32 tile, 2x2 per thread. grid (8,4,8)
__global__ __launch_bounds__(256) void syrk32(const float* __restrict__ Kf,
    const float* __restrict__ V, float* __restrict__ Cp)
{
  int dt = blockIdx.x, ks = blockIdx.y, b = blockIdx.z;
  __shared__ __align__(16) float sa[32*128];
  __shared__ __align__(16) float sb[32*128];
  int tx = threadIdx.x & 15, ty = threadIdx.x >> 4;
  const float* Ab = Kf + (((size_t)b*32)<<12);
  const float* Bb = V  + (((size_t)b*256 + dt*32)<<12);
  float acc[2][2] = {};
  for (int k0 = ks<<10; k0 < (ks<<10)+1024; k0 += 128){
    __syncthreads();
#pragma unroll
    for (int i=0;i<4;i++){
      int fi = threadIdx.x + i*256;
      int r = fi >> 5, j = fi & 31;
      *(float4*)&sa[swz(r,j)] = *(const float4*)&Ab[((size_t)r<<12) + k0 + (j<<2)];
      *(float4*)&sb[swz(r,j)] = *(const float4*)&Bb[((size_t)r<<12) + k0 + (j<<2)];
    }
    __syncthreads();
#pragma unroll 4
    for (int jj=0;jj<32;jj++){
      float4 av[2], bv[2];
#pragma unroll
      for (int i=0;i<2;i++) av[i] = *(const float4*)&sa[swz(2*ty+i,jj)];
#pragma unroll
      for (int i=0;i<2;i++) bv[i] = *(const float4*)&sb[swz(2*tx+i,jj)];
#pragma unroll
      for (int i=0;i<2;i++)
#pragma unroll
        for (int j2=0;j2<2;j2++)
          acc[i][j2] = fmaf(av[i].w,bv[j2].w, fmaf(av[i].z,bv[j2].z,
                       fmaf(av[i].y,bv[j2].y, fmaf(av[i].x,bv[j2].x, acc[i][j2]))));
    }
  }
  float* Cb = Cp + ((size_t)ks*8 + b)*8192;
#pragma unroll
  for (int i=0;i<2;i++)
#pragma unroll
    for (int j2=0;j2<2;j2++)
      Cb[(size_t)(2*ty+i)*256 + dt*32 + 2*tx + j2] = acc[i][j2];
}

__global__ __launch_bounds__(256) void kv_combine(const float* __restrict__ p,
    float* __restrict__ o)
{
  int i = blockIdx.x*256 + threadIdx.x;
  o[i] = p[i] + p[i+65536] + p[i+131072] + p[i+196608];
}

// ---- softmax of (rowmax - e), summing 4 K-split partials on the way in
__global__ __launch_bounds__(256) void softmax4(const float* __restrict__ Ep,
    float* __restrict__ att)
{
  size_t base = (size_t)blockIdx.x << 8;
  int d = threadIdx.x;
  float ed = Ep[base+d] + Ep[base+d+524288] + Ep[base+d+1048576] + Ep[base+d+1572864];
  __shared__ float red[4];
  int lane = d&63, wid = d>>6;
  float v = ed;
  for (int off=32;off;off>>=1) v = fmaxf(v, __shfl_down(v,off));
  if(lane==0) red[wid]=v;
  __syncthreads();
  float rowmax = fmaxf(fmaxf(red[0],red[1]),fmaxf(red[2],red[3]));
  __syncthreads();
  float s = rowmax - ed;
  float v2 = s;
  for (int off=32;off;off>>=1) v2 = fmaxf(v2, __shfl_down(v2,off));
  if(lane==0) red[wid]=v2;
  __syncthreads();
  float smax = fmaxf(fmaxf(red[0],red[1]),fmaxf(red[2],red[3]));
  __syncthreads();
  float p = expf(s - smax);
  float sv = p;
  for (int off=32;off;off>>=1) sv += __shfl_down(sv,off);
  if(lane==0) red[wid]=sv;
  __syncthreads();
  float sum = red[0]+red[1]+red[2]+red[3];
  att[base+d] = p/sum;
}

// ============================================================================
// unchanged small kernels
// ============================================================================
__global__ __launch_bounds__(256) void dw_norm_lit(const float* __restrict__ pw,
    float* __restrict__ z1, const float* __restrict__ dww,
    const float* __restrict__ cbs, const float* __restrict__ cbt,
    const float* __restrict__ ns, const float* __restrict__ nt)
{
  size_t idx = (size_t)blockIdx.x*256 + threadIdx.x;
  int n = (int)(idx & 4095);
  int c = (int)((idx>>12) & 255);
  int h = n>>6, wq = n&63;
  const float* p = pw + (idx - n);
  float acc = 0.f;
  for(int i=0;i<3;i++){
    int hh = h+i-1; if((unsigned)hh >= 64u) continue;
    for(int j=0;j<3;j++){
      int ww = wq+j-1; if((unsigned)ww >= 64u) continue;
      acc += dww[c*9 + i*3 + j] * p[hh*64 + ww];
    }
  }
  float bn = acc*cbs[c] + cbt[c];
  z1[idx] = bn*ns[c] + nt[c];
}

__global__ __launch_bounds__(256) void rowsum_lit(const float* __restrict__ A, float* __restrict__ out)
{
  int x = blockIdx.x;
  const float* ar = A + ((size_t)x << 12);
  float a = 0.f;
  for(int n=threadIdx.x; n<Nn; n+=256) a += ar[n];
  __shared__ float red[4];
  for(int off=32;off;off>>=1) a += __shfl_down(a,off);
  int lane = threadIdx.x&63, wid = threadIdx.x>>6;
  if(lane==0) red[wid]=a;
  __syncthreads();
  if(threadIdx.x==0) out[x] = red[0]+red[1]+red[2]+red[3];
}

__global__ __launch_bounds__(256) void inv_lit(const float* __restrict__ Qf,
    const float* __restrict__ Ks, float* __restrict__ invb)
{
  size_t idx = (size_t)blockIdx.x*256 + threadIdx.x;
  int b = (int)(idx>>12);
  const float* qb = Qf + ((size_t)b*Mm << 12) + (int)(idx&4095);
  const float* ks = Ks + b*Mm;
  float s = 0.f;
  for(int m=0;m<Mm;m++) s += qb[(size_t)m<<12]*(ks[m]+EPSc);
  invb[idx] = 1.f/s;
}

__global__ __launch_bounds__(256) void final_y(const float* __restrict__ yin,
    const float* __restrict__ acc, const float* __restrict__ b2,
    const float* __restrict__ s2, const float* __restrict__ t2, float* __restrict__ out)
{
  size_t idx = (size_t)blockIdx.x*256 + threadIdx.x;
  int c = (int)((idx>>12) & 255);
  float y2 = (acc[idx] + b2[c])*s2[c] + t2[c];
  out[ACT + idx] = yin[idx] + y2;
}

__global__ __launch_bounds__(256) void final_x(const float* __restrict__ xin,
    const float* __restrict__ acc, const float* __restrict__ b2,
    const float* __restrict__ s2, const float* __restrict__ t2, float* __restrict__ out)
{
  size_t idx = (size_t)blockIdx.x*256 + threadIdx.x;
  int c = (int)((idx>>12) & 255);
  float x2 = (acc[idx] + b2[c])*s2[c] + t2[c];
  out[idx] = xin[idx] + x2 + out[ACT + idx];
}

extern "C" void kernel_launch(void* const* d_in, const int* in_sizes, int n_in,
                              void* d_out, int out_size, void* d_ws, size_t ws_size,
                              hipStream_t stream)
{
  (void)in_sizes; (void)n_in; (void)out_size; (void)ws_size;
  const float* xin  = (const float*)d_in[0];
  const float* yin  = (const float*)d_in[1];
  const float* pw_w = (const float*)d_in[2];
  const float* dw_w = (const float*)d_in[3];
  const float* cbs  = (const float*)d_in[4];
  const float* cbt  = (const float*)d_in[5];
  const float* ns   = (const float*)d_in[6];
  const float* nt   = (const float*)d_in[7];
  const float* q_w  = (const float*)d_in[8];
  const float* k_w  = (const float*)d_in[9];
  const float* v_w  = (const float*)d_in[10];
  const float* gk   = (const float*)d_in[11];
  const float* gc   = (const float*)d_in[12];
  const float* fc1_w= (const float*)d_in[13];
  const float* fc1_b= (const float*)d_in[14];
  const float* bn1s = (const float*)d_in[15];
  const float* bn1t = (const float*)d_in[16];
  const float* fc2_w= (const float*)d_in[17];
  const float* fc2_b= (const float*)d_in[18];
  const float* bn2s = (const float*)d_in[19];
  const float* bn2t = (const float*)d_in[20];

  char* ws = (char*)d_ws;
  // layout identical to previous round; energy/KV partials borrow the px_x
  // region (dead until t=1's catt_tile, which runs after softmax4/kv_combine).
  float* A    = (float*)(ws);                 // 0..32M: pw scratch / V / hid chunk
  float* x1   = (float*)(ws + 33554432);      // 32..64M fp32 [B,C,N]
  float* y1   = (float*)(ws + 67108864);      // 64..96M
  bf16*  px_y = (bf16*) (ws + 100663296);     // 96..112M bf16
  bf16*  px_x = (bf16*) (ws + 117440512);     // 112..128M bf16
  float* Ep   = (float*)(ws + 117440512);     // scratch: 4x2M energy partials
  float* KVp  = (float*)(ws + 117440512 + 8388608); // scratch: 4x256K KV partials
  float* Qf   = (float*)(ws + 134217728);     // 128..132M fp32 [B,32,N]
  float* Kf   = (float*)(ws + 138412032);     // 132..136M
  float* Eng  = (float*)(ws + 142606336);     // 136..138M fp32 [B,256,256] (att)
  float* KVf  = (float*)(ws + 144703488);     // 256K fp32 [B,32,256]
  float* Ksf  = (float*)(ws + 144965632);     // 1K  [B,32]
  float* invb = (float*)(ws + 144966656);     // 128K [B,N]
  float* accb = (float*)(ws + 33554432);      // phase3: overlays dead x1

  dim3 blk(256);
  dim3 gO256(16,16,8), gO32(16,2,8), gE(16,4,8), gKV(8,4,8);

  // Phase 1: z1 = norm(bn(dw3(pw(z))))
  c1_tile<EPI_NONE,float,float><<<gO256,blk,0,stream>>>(xin, pw_w, A, 256);
  dw_norm_lit<<<dim3(32768),blk,0,stream>>>(A, x1, dw_w, cbs, cbt, ns, nt);
  c1_tile<EPI_NONE,float,float><<<gO256,blk,0,stream>>>(yin, pw_w, A, 256);
  dw_norm_lit<<<dim3(32768),blk,0,stream>>>(A, y1, dw_w, cbs, cbt, ns, nt);

  // Phase 2
  for (int t=0;t<2;t++){
    const float* z1    = (t==0) ? x1 : y1;
    const float* other = (t==0) ? y1 : x1;
    bf16* pxout        = (t==0) ? px_y : px_x;
    c1_tile<EPI_SOFTPLUS,float,float><<<gO32,blk,0,stream>>>(z1, q_w, Qf, 32);
    c1_tile<EPI_SOFTPLUS,float,float><<<gO32,blk,0,stream>>>(z1, k_w, Kf, 32);
    c1_tile<EPI_NONE,float,float><<<gO256,blk,0,stream>>>(z1, v_w, A, 256);   // V
    syrk32<<<gKV,blk,0,stream>>>(Kf, A, KVp);                                 // KV partials
    kv_combine<<<dim3(256),blk,0,stream>>>(KVp, KVf);
    rowsum_lit<<<dim3(256),blk,0,stream>>>(Kf, Ksf);
    inv_lit<<<dim3(128),blk,0,stream>>>(Qf, Ksf, invb);
    syrk64<<<gE,blk,0,stream>>>(z1, Ep);                                      // energy partials
    softmax4<<<dim3(2048),blk,0,stream>>>(Ep, Eng);                           // att
    catt_tile<<<gO256,blk,0,stream>>>(z1, other, Qf, KVf, invb, Eng,
                                      gk, gc, ns, nt, pxout);
  }

  // Phase 3: MLPs (4 K-chunks; hid chunk fp32 in A, fp32 accumulate in accb)
  for (int s=0;s<2;s++){
    const bf16* px = (s==0) ? px_y : px_x;
    for (int q=0;q<4;q++){
      fc1_tile<<<gO256,blk,0,stream>>>(px, fc1_w + (size_t)q*65536, A,
                                       fc1_b + q*256, bn1s + q*256, bn1t + q*256);
      if (q==0) fc2_tile<1><<<gO256,blk,0,stream>>>(A, fc2_w + q*256, accb);
      else      fc2_tile<0><<<gO256,blk,0,stream>>>(A, fc2_w + q*256, accb);
    }
    if (s==0) final_y<<<dim3(32768),blk,0,stream>>>(yin, accb, fc2_b, bn2s, bn2t, (float*)d_out);
    else      final_x<<<dim3(32768),blk,0,stream>>>(xin, accb, fc2_b, bn2s, bn2t, (float*)d_out);
  }
}

// Round 2
// 1016.943 us; speedup vs baseline: 15.0728x; 2.5638x over previous
//
#include <hip/hip_runtime.h>
#include <hip/hip_bf16.h>
#include <math.h>

typedef __hip_bfloat16 bf16;
typedef unsigned short u16;
#define DEV __device__ __forceinline__

DEV float tofl(float v){ return v; }
DEV float tofl(bf16 v){ return __bfloat162float(v); }
DEV bf16  f2b(float v){ return __float2bfloat16(v); }
DEV u16   f2bu(float v){ bf16 h = f2b(v); u16 u; __builtin_memcpy(&u,&h,2); return u; }

static constexpr int Cc=256, Nn=4096, Mm=32;
static constexpr size_t ACT = (size_t)8*Cc*Nn;
static constexpr float EPSc = 1e-6f;

typedef __attribute__((ext_vector_type(8))) __bf16 bf16x8;
typedef __attribute__((ext_vector_type(4))) float  f32x4;

// ============================================================================
// fp32 16-way register-blocked MAC (kept for pw conv + Q/K convs: fp32 paths)
// ============================================================================
DEV void mac16(const float* __restrict__ inb, const float* __restrict__ wb,
               int WS, float* __restrict__ acc)
{
  for (int k=0;k<256;k+=4){
    float a0 = inb[(size_t)(k+0)<<12];
    float a1 = inb[(size_t)(k+1)<<12];
    float a2 = inb[(size_t)(k+2)<<12];
    float a3 = inb[(size_t)(k+3)<<12];
#pragma unroll
    for (int oo=0;oo<16;oo++){
      const float* wr = wb + (size_t)oo*WS + k;
      acc[oo] = fmaf(a3,wr[3],fmaf(a2,wr[2],fmaf(a1,wr[1],fmaf(a0,wr[0],acc[oo]))));
    }
  }
}

// ---- fp32 1x1 conv (pw conv only), 16 out-channels/block: grid (16,16,8)
__global__ __launch_bounds__(256) void c1_tile(const float* __restrict__ in,
    const float* __restrict__ w, float* __restrict__ out)
{
  int n  = blockIdx.x*256 + threadIdx.x;
  int o0 = blockIdx.y*16;
  int b  = blockIdx.z;
  const float* inb = in + (((size_t)b*256)<<12) + n;
  float acc[16] = {};
  mac16(inb, w + (size_t)o0*256, 256, acc);
#pragma unroll
  for (int oo=0;oo<16;oo++)
    out[(((size_t)b*256 + o0 + oo)<<12) + n] = acc[oo];
}

// ---- fused Q+K softplus convs: grid (16,4,8); y<2 -> Q chunk, else K chunk
__global__ __launch_bounds__(256) void qk_tile(const float* __restrict__ z1,
    const float* __restrict__ qw, const float* __restrict__ kw,
    float* __restrict__ Qf, float* __restrict__ Kf)
{
  int n  = blockIdx.x*256 + threadIdx.x;
  int y  = blockIdx.y;
  int o0 = (y&1)*16;
  int b  = blockIdx.z;
  const float* w   = (y<2) ? qw : kw;
  float*       out = (y<2) ? Qf : Kf;
  const float* inb = z1 + (((size_t)b*256)<<12) + n;
  float acc[16] = {};
  mac16(inb, w + (size_t)o0*256, 256, acc);
#pragma unroll
  for (int oo=0;oo<16;oo++){
    float a = acc[oo];
    a = fmaxf(a,0.f) + log1pf(expf(-fabsf(a)));      // softplus
    out[(((size_t)b*32 + o0 + oo)<<12) + n] = a;
  }
}

// ============================================================================
// bf16 MFMA GEMM: C[b] = A[b] (MxK, row-major bf16) x B[b] (KxN via n-major
// [4096][K] bf16).  128x128 tile, BK=64, 4 waves (2x2), 16x16x32 MFMA.
// LDS tiles [128 rows][64 k] with 16B-granule XOR swizzle (T2).
// Double-buffered; loads issued before compute (T14).
// OMODE 0: fp32 c-major out [b][M][4096].  OMODE 1 (fc1): bf16 n-major out
// [b][4096][1024] with relu6((x+bia)*scl+sht).
// ============================================================================
struct StageRegs { int4 a[4], b[4]; };

DEV void stage_load(const u16* __restrict__ gA, int ldA,
                    const u16* __restrict__ gB, int ldB, int tid, StageRegs& r)
{
  int row = tid>>3, g = tid&7;
#pragma unroll
  for(int i=0;i<4;i++){
    r.a[i] = *(const int4*)(gA + (size_t)(row+32*i)*ldA + g*8);
    r.b[i] = *(const int4*)(gB + (size_t)(row+32*i)*ldB + g*8);
  }
}
DEV void stage_write(u16* __restrict__ sA, u16* __restrict__ sB,
                     int tid, const StageRegs& r)
{
  int row = tid>>3, g = tid&7;
#pragma unroll
  for(int i=0;i<4;i++){
    int rr = row+32*i;
    int gg = ((g ^ (rr&7))<<3);
    *(int4*)(sA + rr*64 + gg) = r.a[i];
    *(int4*)(sB + rr*64 + gg) = r.b[i];
  }
}

template<int KDIM, int OMODE>
__global__ __launch_bounds__(256,2) void gemm_bf16(
    const u16* __restrict__ A, long sAb,
    const u16* __restrict__ B,
    float* __restrict__ Cf, u16* __restrict__ Cb,
    const float* __restrict__ bia, const float* __restrict__ scl,
    const float* __restrict__ sht)
{
  __shared__ __align__(16) u16 sA[2][8192];
  __shared__ __align__(16) u16 sB[2][8192];
  int tid = threadIdx.x;
  int nt = blockIdx.x, mt = blockIdx.y, b = blockIdx.z;
  const u16* gA = A + (size_t)b*sAb + (size_t)mt*128*KDIM;
  const u16* gB = B + ((size_t)b*4096 + (size_t)nt*128)*KDIM;
  int w = tid>>6, l = tid&63;
  int wr = w>>1, wc = w&1;
  int l15 = l&15, lg = l>>4;
  f32x4 acc[4][4] = {};
  StageRegs r;
  stage_load(gA, KDIM, gB, KDIM, tid, r);
  stage_write(sA[0], sB[0], tid, r);
  __syncthreads();
  constexpr int NT = KDIM/64;
  for(int t=0;t<NT;t++){
    int cur = t&1;
    if(t+1<NT) stage_load(gA + (t+1)*64, KDIM, gB + (t+1)*64, KDIM, tid, r);
#pragma unroll
    for(int ks=0;ks<2;ks++){
      bf16x8 af[4], bfr[4];
#pragma unroll
      for(int m=0;m<4;m++){
        int row = wr*64 + m*16 + l15;
        int g = ks*4 + lg;
        af[m] = *(const bf16x8*)(&sA[cur][row*64 + ((g^(row&7))<<3)]);
      }
#pragma unroll
      for(int nn=0;nn<4;nn++){
        int row = wc*64 + nn*16 + l15;
        int g = ks*4 + lg;
        bfr[nn] = *(const bf16x8*)(&sB[cur][row*64 + ((g^(row&7))<<3)]);
      }
#pragma unroll
      for(int m=0;m<4;m++)
#pragma unroll
        for(int nn=0;nn<4;nn++)
          acc[m][nn] = __builtin_amdgcn_mfma_f32_16x16x32_bf16(af[m], bfr[nn], acc[m][nn], 0,0,0);
    }
    if(t+1<NT) stage_write(sA[cur^1], sB[cur^1], tid, r);
    __syncthreads();
  }
  int obase = mt*128 + wr*64;
  int nbase = nt*128 + wc*64;
  if (OMODE==0){
    size_t Mrows = (size_t)gridDim.y*128;
#pragma unroll
    for(int m=0;m<4;m++)
#pragma unroll
      for(int nn=0;nn<4;nn++){
        int o_ = obase + m*16 + (lg<<2);
        int n_ = nbase + nn*16 + l15;
        float* dst = Cf + (((size_t)b*Mrows + o_)<<12) + n_;
#pragma unroll
        for(int i=0;i<4;i++) dst[(size_t)i<<12] = acc[m][nn][i];
      }
  } else {
#pragma unroll
    for(int m=0;m<4;m++)
#pragma unroll
      for(int nn=0;nn<4;nn++){
        int o_ = obase + m*16 + (lg<<2);
        int n_ = nbase + nn*16 + l15;
        union { u16 u[4]; uint2 v; } pk;
#pragma unroll
        for(int i=0;i<4;i++){
          int o = o_+i;
          float a2 = (acc[m][nn][i] + bia[o])*scl[o] + sht[o];
          pk.u[i] = f2bu(fminf(fmaxf(a2,0.f),6.f));
        }
        *(uint2*)(Cb + ((size_t)b*4096 + (size_t)n_)*1024 + o_) = pk.v;
      }
  }
}

// ============================================================================
// fp32 SYRK kernels (energy MUST stay fp32 — feeds softmax exponent)
// ============================================================================
DEV int swz(int r, int j){ return r*128 + ((j ^ ((r>>2)&7))<<2); }

__global__ __launch_bounds__(256) void syrk64(const float* __restrict__ Z,
    float* __restrict__ Cp)
{
  int ct = blockIdx.x >> 2, dt = blockIdx.x & 3;
  int ks = blockIdx.y, b = blockIdx.z;
  __shared__ __align__(16) float sa[64*128];
  __shared__ __align__(16) float sb[64*128];
  int tx = threadIdx.x & 15, ty = threadIdx.x >> 4;
  const float* Ab = Z + (((size_t)b*256 + ct*64)<<12);
  const float* Bb = Z + (((size_t)b*256 + dt*64)<<12);
  float acc[4][4] = {};
  for (int k0 = ks<<10; k0 < (ks<<10)+1024; k0 += 128){
    __syncthreads();
#pragma unroll
    for (int i=0;i<8;i++){
      int fi = threadIdx.x + i*256;
      int r = fi >> 5, j = fi & 31;
      *(float4*)&sa[swz(r,j)] = *(const float4*)&Ab[((size_t)r<<12) + k0 + (j<<2)];
      *(float4*)&sb[swz(r,j)] = *(const float4*)&Bb[((size_t)r<<12) + k0 + (j<<2)];
    }
    __syncthreads();
#pragma unroll 2
    for (int jj=0;jj<32;jj++){
      float4 av[4], bv[4];
#pragma unroll
      for (int i=0;i<4;i++) av[i] = *(const float4*)&sa[swz(4*ty+i,jj)];
#pragma unroll
      for (int i=0;i<4;i++) bv[i] = *(const float4*)&sb[swz(4*tx+i,jj)];
#pragma unroll
      for (int i=0;i<4;i++)
#pragma unroll
        for (int j2=0;j2<4;j2++)
          acc[i][j2] = fmaf(av[i].w,bv[j2].w, fmaf(av[i].z,bv[j2].z,
                       fmaf(av[i].y,bv[j2].y, fmaf(av[i].x,bv[j2].x, acc[i][j2]))));
    }
  }
  float* Cb = Cp + ((size_t)ks*8 + b)*65536;
#pragma unroll
  for (int i=0;i<4;i++)
#pragma unroll
    for (int j2=0;j2<4;j2++)
      Cb[(size_t)(ct*64 + 4*ty + i)*256 + dt*64 + 4*tx + j2] = acc[i][j2];
}

__global__ __launch_bounds__(256) void syrk32(const float* __restrict__ Kf,
    const float* __restrict__ V, float* __restrict__ Cp)
{
  int dt = blockIdx.x, ks = blockIdx.y, b = blockIdx.z;
  __shared__ __align__(16) float sa[32*128];
  __shared__ __align__(16) float sb[32*128];
  int tx = threadIdx.x & 15, ty = threadIdx.x >> 4;
  const float* Ab = Kf + (((size_t)b*32)<<12);
  const float* Bb = V  + (((size_t)b*256 + dt*32)<<12);
  float acc[2][2] = {};
  for (int k0 = ks<<10; k0 < (ks<<10)+1024; k0 += 128){
    __syncthreads();
#pragma unroll
    for (int i=0;i<4;i++){
      int fi = threadIdx.x + i*256;
      int r = fi >> 5, j = fi & 31;
      *(float4*)&sa[swz(r,j)] = *(const float4*)&Ab[((size_t)r<<12) + k0 + (j<<2)];
      *(float4*)&sb[swz(r,j)] = *(const float4*)&Bb[((size_t)r<<12) + k0 + (j<<2)];
    }
    __syncthreads();
#pragma unroll 4
    for (int jj=0;jj<32;jj++){
      float4 av[2], bv[2];
#pragma unroll
      for (int i=0;i<2;i++) av[i] = *(const float4*)&sa[swz(2*ty+i,jj)];
#pragma unroll
      for (int i=0;i<2;i++) bv[i] = *(const float4*)&sb[swz(2*tx+i,jj)];
#pragma unroll
      for (int i=0;i<2;i++)
#pragma unroll
        for (int j2=0;j2<2;j2++)
          acc[i][j2] = fmaf(av[i].w,bv[j2].w, fmaf(av[i].z,bv[j2].z,
                       fmaf(av[i].y,bv[j2].y, fmaf(av[i].x,bv[j2].x, acc[i][j2]))));
    }
  }
  float* Cb = Cp + ((size_t)ks*8 + b)*8192;
#pragma unroll
  for (int i=0;i<2;i++)
#pragma unroll
    for (int j2=0;j2<2;j2++)
      Cb[(size_t)(2*ty+i)*256 + dt*32 + 2*tx + j2] = acc[i][j2];
}

__global__ __launch_bounds__(256) void kv_combine(const float* __restrict__ p,
    float* __restrict__ o)
{
  int i = blockIdx.x*256 + threadIdx.x;
  o[i] = p[i] + p[i+65536] + p[i+131072] + p[i+196608];
}

// ---- softmax of (rowmax - e), summing 4 K-split partials; bf16 att out
__global__ __launch_bounds__(256) void softmax4(const float* __restrict__ Ep,
    u16* __restrict__ att)
{
  size_t base = (size_t)blockIdx.x << 8;
  int d = threadIdx.x;
  float ed = Ep[base+d] + Ep[base+d+524288] + Ep[base+d+1048576] + Ep[base+d+1572864];
  __shared__ float red[4];
  int lane = d&63, wid = d>>6;
  float v = ed;
  for (int off=32;off;off>>=1) v = fmaxf(v, __shfl_down(v,off));
  if(lane==0) red[wid]=v;
  __syncthreads();
  float rowmax = fmaxf(fmaxf(red[0],red[1]),fmaxf(red[2],red[3]));
  __syncthreads();
  float s = rowmax - ed;
  float v2 = s;
  for (int off=32;off;off>>=1) v2 = fmaxf(v2, __shfl_down(v2,off));
  if(lane==0) red[wid]=v2;
  __syncthreads();
  float smax = fmaxf(fmaxf(red[0],red[1]),fmaxf(red[2],red[3]));
  __syncthreads();
  float p = expf(s - smax);
  float sv = p;
  for (int off=32;off;off>>=1) sv += __shfl_down(sv,off);
  if(lane==0) red[wid]=sv;
  __syncthreads();
  float sum = red[0]+red[1]+red[2]+red[3];
  att[base+d] = f2bu(p/sum);
}

// ============================================================================
// light epilogue: px[b][n][c] = bf16( other*(2z + gc*s1 + gk*inv*sum_m Q*KV)
//                                     *ns[c] + nt[c] ),  n-major output
// ============================================================================
__global__ __launch_bounds__(256) void catt_px(const float* __restrict__ z1,
    const float* __restrict__ other, const float* __restrict__ Qf,
    const float* __restrict__ KVf, const float* __restrict__ invb,
    const float* __restrict__ s1b, const float* __restrict__ gkp,
    const float* __restrict__ gcp, const float* __restrict__ ns,
    const float* __restrict__ nt, u16* __restrict__ px)
{
  int n  = blockIdx.x*256 + threadIdx.x;
  int c0 = blockIdx.y*16;
  int b  = blockIdx.z;
  const float* qb  = Qf  + (((size_t)b*Mm)<<12) + n;
  const float* kvb = KVf + ((size_t)b<<13) + c0;
  float s2[16] = {};
#pragma unroll
  for (int m=0;m<Mm;m++){
    float qm = qb[(size_t)m<<12];
#pragma unroll
    for (int oo=0;oo<16;oo++) s2[oo] = fmaf(qm, kvb[m*256 + oo], s2[oo]);
  }
  float invv = invb[((size_t)b<<12)+n];
  float gk = gkp[0], gc = gcp[0];
  union { u16 u[16]; uint4 q[2]; } pk;
#pragma unroll
  for (int oo=0;oo<16;oo++){
    int c = c0+oo;
    size_t idx = (((size_t)b*256 + c)<<12) + n;
    float a = 2.f*z1[idx] + gc*s1b[idx] + gk*s2[oo]*invv;
    pk.u[oo] = f2bu(other[idx]*a*ns[c] + nt[c]);
  }
  u16* dst = px + (((size_t)b*4096 + n)<<8) + c0;
  *(uint4*)dst       = pk.q[0];
  *(uint4*)(dst + 8) = pk.q[1];
}

// ---- fp32 c-major -> bf16 n-major convert (z1 -> z1b), grid (16,16,8)
__global__ __launch_bounds__(256) void cvt_nmajor(const float* __restrict__ z,
    u16* __restrict__ zb)
{
  int n  = blockIdx.x*256 + threadIdx.x;
  int c0 = blockIdx.y*16;
  int b  = blockIdx.z;
  union { u16 u[16]; uint4 q[2]; } pk;
#pragma unroll
  for (int oo=0;oo<16;oo++)
    pk.u[oo] = f2bu(z[(((size_t)b*256 + c0 + oo)<<12) + n]);
  u16* dst = zb + (((size_t)b*4096 + n)<<8) + c0;
  *(uint4*)dst       = pk.q[0];
  *(uint4*)(dst + 8) = pk.q[1];
}

// ---- fp32 -> bf16 weight convert
__global__ __launch_bounds__(256) void cvt_w(const float* __restrict__ s,
    u16* __restrict__ d)
{
  int i = blockIdx.x*256 + threadIdx.x;
  d[i] = f2bu(s[i]);
}

// ============================================================================
// unchanged small kernels
// ============================================================================
__global__ __launch_bounds__(256) void dw_norm_lit(const float* __restrict__ pw,
    float* __restrict__ z1, const float* __restrict__ dww,
    const float* __restrict__ cbs, const float* __restrict__ cbt,
    const float* __restrict__ ns, const float* __restrict__ nt)
{
  size_t idx = (size_t)blockIdx.x*256 + threadIdx.x;
  int n = (int)(idx & 4095);
  int c = (int)((idx>>12) & 255);
  int h = n>>6, wq = n&63;
  const float* p = pw + (idx - n);
  float acc = 0.f;
  for(int i=0;i<3;i++){
    int hh = h+i-1; if((unsigned)hh >= 64u) continue;
    for(int j=0;j<3;j++){
      int ww = wq+j-1; if((unsigned)ww >= 64u) continue;
      acc += dww[c*9 + i*3 + j] * p[hh*64 + ww];
    }
  }
  float bn = acc*cbs[c] + cbt[c];
  z1[idx] = bn*ns[c] + nt[c];
}

__global__ __launch_bounds__(256) void rowsum_lit(const float* __restrict__ A, float* __restrict__ out)
{
  int x = blockIdx.x;
  const float* ar = A + ((size_t)x << 12);
  float a = 0.f;
  for(int n=threadIdx.x; n<Nn; n+=256) a += ar[n];
  __shared__ float red[4];
  for(int off=32;off;off>>=1) a += __shfl_down(a,off);
  int lane = threadIdx.x&63, wid = threadIdx.x>>6;
  if(lane==0) red[wid]=a;
  __syncthreads();
  if(threadIdx.x==0) out[x] = red[0]+red[1]+red[2]+red[3];
}

__global__ __launch_bounds__(256) void inv_lit(const float* __restrict__ Qf,
    const float* __restrict__ Ks, float* __restrict__ invb)
{
  size_t idx = (size_t)blockIdx.x*256 + threadIdx.x;
  int b = (int)(idx>>12);
  const float* qb = Qf + ((size_t)b*Mm << 12) + (int)(idx&4095);
  const float* ks = Ks + b*Mm;
  float s = 0.f;
  for(int m=0;m<Mm;m++) s += qb[(size_t)m<<12]*(ks[m]+EPSc);
  invb[idx] = 1.f/s;
}

__global__ __launch_bounds__(256) void final_y(const float* __restrict__ yin,
    const float* __restrict__ acc, const float* __restrict__ b2,
    const float* __restrict__ s2, const float* __restrict__ t2, float* __restrict__ out)
{
  size_t idx = (size_t)blockIdx.x*256 + threadIdx.x;
  int c = (int)((idx>>12) & 255);
  float y2 = (acc[idx] + b2[c])*s2[c] + t2[c];
  out[ACT + idx] = yin[idx] + y2;
}

__global__ __launch_bounds__(256) void final_x(const float* __restrict__ xin,
    const float* __restrict__ acc, const float* __restrict__ b2,
    const float* __restrict__ s2, const float* __restrict__ t2, float* __restrict__ out)
{
  size_t idx = (size_t)blockIdx.x*256 + threadIdx.x;
  int c = (int)((idx>>12) & 255);
  float x2 = (acc[idx] + b2[c])*s2[c] + t2[c];
  out[idx] = xin[idx] + x2 + out[ACT + idx];
}

extern "C" void kernel_launch(void* const* d_in, const int* in_sizes, int n_in,
                              void* d_out, int out_size, void* d_ws, size_t ws_size,
                              hipStream_t stream)
{
  (void)in_sizes; (void)n_in; (void)out_size; (void)ws_size;
  const float* xin  = (const float*)d_in[0];
  const float* yin  = (const float*)d_in[1];
  const float* pw_w = (const float*)d_in[2];
  const float* dw_w = (const float*)d_in[3];
  const float* cbs  = (const float*)d_in[4];
  const float* cbt  = (const float*)d_in[5];
  const float* ns   = (const float*)d_in[6];
  const float* nt   = (const float*)d_in[7];
  const float* q_w  = (const float*)d_in[8];
  const float* k_w  = (const float*)d_in[9];
  const float* v_w  = (const float*)d_in[10];
  const float* gk   = (const float*)d_in[11];
  const float* gc   = (const float*)d_in[12];
  const float* fc1_w= (const float*)d_in[13];
  const float* fc1_b= (const float*)d_in[14];
  const float* bn1s = (const float*)d_in[15];
  const float* bn1t = (const float*)d_in[16];
  const float* fc2_w= (const float*)d_in[17];
  const float* fc2_b= (const float*)d_in[18];
  const float* bn2s = (const float*)d_in[19];
  const float* bn2t = (const float*)d_in[20];

  char* ws = (char*)d_ws;
  // ---- workspace (same 145,097,728-byte footprint as the proven layout) ----
  float* A    = (float*)(ws);                 // 0..32M: pw scratch / V / Ep / s1 / accb
  float* x1   = (float*)(ws + 33554432);      // 32..64M fp32
  float* y1   = (float*)(ws + 67108864);      // 64..96M fp32
  u16*   hid  = (u16*)  (ws + 33554432);      // phase3: bf16 [8][4096][1024] = 64M (over x1+y1)
  u16*   px_y = (u16*)  (ws + 100663296);     // 96..112M bf16 n-major [8][4096][256]
  u16*   px_x = (u16*)  (ws + 117440512);     // 112..128M bf16 n-major
  u16*   z1b  = (u16*)  (ws + 117440512);     // phase2 scratch over px_x (dead until t=1 end)
  float* Qf   = (float*)(ws + 134217728);     // 128..132M fp32 [8,32,4096]
  float* Kf   = (float*)(ws + 138412032);     // 132..136M
  u16*   attb = (u16*)  (ws + 142606336);     // 136..137M bf16 [8][256][256]
  u16*   fc1wb= (u16*)  (ws + 142606336);     // phase3 (attb dead): 512K
  u16*   fc2wb= (u16*)  (ws + 142606336 + 524288); // 512K
  float* KVf  = (float*)(ws + 143654912);     // 256K fp32 [8,32,256]
  float* Ksf  = (float*)(ws + 143917056);     // 1K
  float* invb = (float*)(ws + 143918080);     // 128K
  float* KVp  = (float*)(ws + 144049152);     // 1M KV partials (per-t)
  u16*   vwb  = (u16*)  (ws + 144049152);     // 128K, re-converted per t (KVp clobbers)
  float* Ep   = A;                            // energy partials 8M (over dead V)
  float* accb = A;                            // phase3 accumulate

  dim3 blk(256);
  dim3 gPX(16,16,8), gQK(16,4,8), gE(16,4,8), gKV(8,4,8);
  dim3 gG256(32,2,8), gFC1(32,8,8), gFC2(32,2,8);

  // Phase 1: z1 = norm(bn(dw3(pw(z))))  (fp32 — z1 feeds the energy exponent)
  c1_tile<<<gPX,blk,0,stream>>>(xin, pw_w, A);
  dw_norm_lit<<<dim3(32768),blk,0,stream>>>(A, x1, dw_w, cbs, cbt, ns, nt);
  c1_tile<<<gPX,blk,0,stream>>>(yin, pw_w, A);
  dw_norm_lit<<<dim3(32768),blk,0,stream>>>(A, y1, dw_w, cbs, cbt, ns, nt);

  // Phase 2
  for (int t=0;t<2;t++){
    const float* z1    = (t==0) ? x1 : y1;
    const float* other = (t==0) ? y1 : x1;
    u16* pxout         = (t==0) ? px_y : px_x;
    cvt_w<<<dim3(256),blk,0,stream>>>(v_w, vwb);                              // 256x256
    cvt_nmajor<<<gPX,blk,0,stream>>>(z1, z1b);
    qk_tile<<<gQK,blk,0,stream>>>(z1, q_w, k_w, Qf, Kf);
    gemm_bf16<256,0><<<gG256,blk,0,stream>>>(vwb, 0, z1b, A, nullptr,
                                             nullptr, nullptr, nullptr);      // V fp32
    syrk32<<<gKV,blk,0,stream>>>(Kf, A, KVp);
    kv_combine<<<dim3(256),blk,0,stream>>>(KVp, KVf);
    rowsum_lit<<<dim3(256),blk,0,stream>>>(Kf, Ksf);
    inv_lit<<<dim3(128),blk,0,stream>>>(Qf, Ksf, invb);
    syrk64<<<gE,blk,0,stream>>>(z1, Ep);                                      // energy (fp32!)
    softmax4<<<dim3(2048),blk,0,stream>>>(Ep, attb);
    gemm_bf16<256,0><<<gG256,blk,0,stream>>>(attb, 65536, z1b, A, nullptr,
                                             nullptr, nullptr, nullptr);      // s1 fp32
    catt_px<<<gPX,blk,0,stream>>>(z1, other, Qf, KVf, invb, A,
                                  gk, gc, ns, nt, pxout);
  }

  // Phase 3: MLPs via bf16 MFMA (full K, no chunking)
  cvt_w<<<dim3(1024),blk,0,stream>>>(fc1_w, fc1wb);                           // 1024x256
  cvt_w<<<dim3(1024),blk,0,stream>>>(fc2_w, fc2wb);                           // 256x1024
  for (int s=0;s<2;s++){
    const u16* px = (s==0) ? px_y : px_x;
    gemm_bf16<256,1><<<gFC1,blk,0,stream>>>(fc1wb, 0, px, nullptr, hid,
                                            fc1_b, bn1s, bn1t);               // hid bf16 n-major
    gemm_bf16<1024,0><<<gFC2,blk,0,stream>>>(fc2wb, 0, hid, accb, nullptr,
                                             nullptr, nullptr, nullptr);      // accb fp32
    if (s==0) final_y<<<dim3(32768),blk,0,stream>>>(yin, accb, fc2_b, bn2s, bn2t, (float*)d_out);
    else      final_x<<<dim3(32768),blk,0,stream>>>(xin, accb, fc2_b, bn2s, bn2t, (float*)d_out);
  }
}

// Round 3
// 865.717 us; speedup vs baseline: 17.7057x; 1.1747x over previous
//
#include <hip/hip_runtime.h>
#include <hip/hip_bf16.h>
#include <math.h>

typedef __hip_bfloat16 bf16;
typedef unsigned short u16;
#define DEV __device__ __forceinline__

DEV float tofl(float v){ return v; }
DEV float tofl(bf16 v){ return __bfloat162float(v); }
DEV bf16  f2b(float v){ return __float2bfloat16(v); }
DEV u16   f2bu(float v){ bf16 h = f2b(v); u16 u; __builtin_memcpy(&u,&h,2); return u; }
DEV float u2f(u16 u){ bf16 h; __builtin_memcpy(&h,&u,2); return __bfloat162float(h); }

static constexpr int Cc=256, Nn=4096, Mm=32;
static constexpr size_t ACT = (size_t)8*Cc*Nn;
static constexpr float EPSc = 1e-6f;

typedef __attribute__((ext_vector_type(8))) __bf16 bf16x8;
typedef __attribute__((ext_vector_type(4))) float  f32x4;

// ============================================================================
// MFMA GEMM building blocks (128x128 tile, BK=64, 4 waves, 16x16x32 bf16,
// XOR-swizzled LDS, double-buffered, load-early/write-late). Proven round 2.
// ============================================================================
struct StageRegs { int4 a[4], b[4]; };

DEV void stage_load(const u16* __restrict__ gA, int ldA,
                    const u16* __restrict__ gB, int ldB, int tid, StageRegs& r)
{
  int row = tid>>3, g = tid&7;
#pragma unroll
  for(int i=0;i<4;i++){
    r.a[i] = *(const int4*)(gA + (size_t)(row+32*i)*ldA + g*8);
    r.b[i] = *(const int4*)(gB + (size_t)(row+32*i)*ldB + g*8);
  }
}
DEV void stage_write(u16* __restrict__ sA, u16* __restrict__ sB,
                     int tid, const StageRegs& r)
{
  int row = tid>>3, g = tid&7;
#pragma unroll
  for(int i=0;i<4;i++){
    int rr = row+32*i;
    int gg = ((g ^ (rr&7))<<3);
    *(int4*)(sA + rr*64 + gg) = r.a[i];
    *(int4*)(sB + rr*64 + gg) = r.b[i];
  }
}

// ---- plain bf16 GEMM (V, att.z, fc1, fc2) — unchanged from round 2
template<int KDIM, int OMODE>
__global__ __launch_bounds__(256,2) void gemm_bf16(
    const u16* __restrict__ A, long sAb,
    const u16* __restrict__ B,
    float* __restrict__ Cf, u16* __restrict__ Cb,
    const float* __restrict__ bia, const float* __restrict__ scl,
    const float* __restrict__ sht)
{
  __shared__ __align__(16) u16 sA[2][8192];
  __shared__ __align__(16) u16 sB[2][8192];
  int tid = threadIdx.x;
  int nt = blockIdx.x, mt = blockIdx.y, b = blockIdx.z;
  const u16* gA = A + (size_t)b*sAb + (size_t)mt*128*KDIM;
  const u16* gB = B + ((size_t)b*4096 + (size_t)nt*128)*KDIM;
  int w = tid>>6, l = tid&63;
  int wr = w>>1, wc = w&1;
  int l15 = l&15, lg = l>>4;
  f32x4 acc[4][4] = {};
  StageRegs r;
  stage_load(gA, KDIM, gB, KDIM, tid, r);
  stage_write(sA[0], sB[0], tid, r);
  __syncthreads();
  constexpr int NT = KDIM/64;
  for(int t=0;t<NT;t++){
    int cur = t&1;
    if(t+1<NT) stage_load(gA + (t+1)*64, KDIM, gB + (t+1)*64, KDIM, tid, r);
#pragma unroll
    for(int ks=0;ks<2;ks++){
      bf16x8 af[4], bfr[4];
#pragma unroll
      for(int m=0;m<4;m++){
        int row = wr*64 + m*16 + l15;
        int g = ks*4 + lg;
        af[m] = *(const bf16x8*)(&sA[cur][row*64 + ((g^(row&7))<<3)]);
      }
#pragma unroll
      for(int nn=0;nn<4;nn++){
        int row = wc*64 + nn*16 + l15;
        int g = ks*4 + lg;
        bfr[nn] = *(const bf16x8*)(&sB[cur][row*64 + ((g^(row&7))<<3)]);
      }
#pragma unroll
      for(int m=0;m<4;m++)
#pragma unroll
        for(int nn=0;nn<4;nn++)
          acc[m][nn] = __builtin_amdgcn_mfma_f32_16x16x32_bf16(af[m], bfr[nn], acc[m][nn], 0,0,0);
    }
    if(t+1<NT) stage_write(sA[cur^1], sB[cur^1], tid, r);
    __syncthreads();
  }
  int obase = mt*128 + wr*64;
  int nbase = nt*128 + wc*64;
  if (OMODE==0){
    size_t Mrows = (size_t)gridDim.y*128;
#pragma unroll
    for(int m=0;m<4;m++)
#pragma unroll
      for(int nn=0;nn<4;nn++){
        int o_ = obase + m*16 + (lg<<2);
        int n_ = nbase + nn*16 + l15;
        float* dst = Cf + (((size_t)b*Mrows + o_)<<12) + n_;
#pragma unroll
        for(int i=0;i<4;i++) dst[(size_t)i<<12] = acc[m][nn][i];
      }
  } else {
#pragma unroll
    for(int m=0;m<4;m++)
#pragma unroll
      for(int nn=0;nn<4;nn++){
        int o_ = obase + m*16 + (lg<<2);
        int n_ = nbase + nn*16 + l15;
        union { u16 u[4]; uint2 v; } pk;
#pragma unroll
        for(int i=0;i<4;i++){
          int o = o_+i;
          float a2 = (acc[m][nn][i] + bia[o])*scl[o] + sht[o];
          pk.u[i] = f2bu(fminf(fmaxf(a2,0.f),6.f));
        }
        *(uint2*)(Cb + ((size_t)b*4096 + (size_t)n_)*1024 + o_) = pk.v;
      }
  }
}

// ---- split-bf16 3-pass GEMM: C = (Ah+Al)(Bh+Bl) ~= AhBh + AhBl + AlBh,
// fp32 MFMA accumulation -> ~1e-5 relative (fp32-equivalent here).
// OMODE 0: fp32 c-major [b][M][4096].  OMODE 2: energy K-split partial
// [ks][b][256][256] fp32.
template<int KTILES, int KSPLIT, int OMODE>
__global__ __launch_bounds__(256,2) void gemm3(
    const u16* __restrict__ Ah, const u16* __restrict__ Al, int ldA, long sAb,
    const u16* __restrict__ Bh, const u16* __restrict__ Bl, int ldB, long sBb,
    float* __restrict__ Cf)
{
  __shared__ __align__(16) u16 sA[2][8192];
  __shared__ __align__(16) u16 sB[2][8192];
  int tid = threadIdx.x;
  int nt = blockIdx.x, mt = blockIdx.y;
  int b  = blockIdx.z / KSPLIT, ks = blockIdx.z % KSPLIT;
  long koff = (long)ks * (KTILES*64);
  const u16* A0 = Ah + (size_t)b*sAb + (size_t)mt*128*ldA + koff;
  const u16* A1 = Al + (size_t)b*sAb + (size_t)mt*128*ldA + koff;
  const u16* B0 = Bh + (size_t)b*sBb + (size_t)nt*128*ldB + koff;
  const u16* B1 = Bl + (size_t)b*sBb + (size_t)nt*128*ldB + koff;
  int w = tid>>6, l = tid&63;
  int wr = w>>1, wc = w&1;
  int l15 = l&15, lg = l>>4;
  f32x4 acc[4][4] = {};
  StageRegs r;
  for(int pass=0; pass<3; ++pass){
    const u16* gA = (pass==2) ? A1 : A0;
    const u16* gB = (pass==1) ? B1 : B0;
    stage_load(gA, ldA, gB, ldB, tid, r);
    stage_write(sA[0], sB[0], tid, r);
    __syncthreads();
    for(int t=0;t<KTILES;t++){
      int cur = t&1;
      if(t+1<KTILES) stage_load(gA + (t+1)*64, ldA, gB + (t+1)*64, ldB, tid, r);
#pragma unroll
      for(int kss=0;kss<2;kss++){
        bf16x8 af[4], bfr[4];
#pragma unroll
        for(int m=0;m<4;m++){
          int row = wr*64 + m*16 + l15;
          int g = kss*4 + lg;
          af[m] = *(const bf16x8*)(&sA[cur][row*64 + ((g^(row&7))<<3)]);
        }
#pragma unroll
        for(int nn=0;nn<4;nn++){
          int row = wc*64 + nn*16 + l15;
          int g = kss*4 + lg;
          bfr[nn] = *(const bf16x8*)(&sB[cur][row*64 + ((g^(row&7))<<3)]);
        }
#pragma unroll
        for(int m=0;m<4;m++)
#pragma unroll
          for(int nn=0;nn<4;nn++)
            acc[m][nn] = __builtin_amdgcn_mfma_f32_16x16x32_bf16(af[m], bfr[nn], acc[m][nn], 0,0,0);
      }
      if(t+1<KTILES) stage_write(sA[cur^1], sB[cur^1], tid, r);
      __syncthreads();
    }
  }
  int obase = mt*128 + wr*64;
  int nbase = nt*128 + wc*64;
  if (OMODE==0){
    size_t Mrows = (size_t)gridDim.y*128;
#pragma unroll
    for(int m=0;m<4;m++)
#pragma unroll
      for(int nn=0;nn<4;nn++){
        int o_ = obase + m*16 + (lg<<2);
        int n_ = nbase + nn*16 + l15;
        float* dst = Cf + (((size_t)b*Mrows + o_)<<12) + n_;
#pragma unroll
        for(int i=0;i<4;i++) dst[(size_t)i<<12] = acc[m][nn][i];
      }
  } else {
    int gridB = gridDim.z / KSPLIT;
    float* Cb = Cf + ((size_t)ks*gridB + b)*65536;
#pragma unroll
    for(int m=0;m<4;m++)
#pragma unroll
      for(int nn=0;nn<4;nn++){
        int o_ = obase + m*16 + (lg<<2);
        int n_ = nbase + nn*16 + l15;
#pragma unroll
        for(int i=0;i<4;i++) Cb[(size_t)(o_+i)*256 + n_] = acc[m][nn][i];
      }
  }
}

// ============================================================================
// conversion kernels
// ============================================================================
// fp32 -> bf16 (plain)
__global__ __launch_bounds__(256) void cvt_w(const float* __restrict__ s,
    u16* __restrict__ d)
{
  int i = blockIdx.x*256 + threadIdx.x;
  d[i] = f2bu(s[i]);
}
// fp32 -> split hi/lo bf16 (weights)
__global__ __launch_bounds__(256) void cvt_wsplit(const float* __restrict__ s,
    u16* __restrict__ dh, u16* __restrict__ dl)
{
  int i = blockIdx.x*256 + threadIdx.x;
  float v = s[i];
  u16 h = f2bu(v);
  dh[i] = h; dl[i] = f2bu(v - u2f(h));
}
// fp32 c-major -> split hi/lo bf16 n-major (pw conv B operand), grid (16,16,8)
__global__ __launch_bounds__(256) void cvt_split_nm(const float* __restrict__ x,
    u16* __restrict__ xh, u16* __restrict__ xl)
{
  int n  = blockIdx.x*256 + threadIdx.x;
  int c0 = blockIdx.y*16;
  int b  = blockIdx.z;
  union { u16 u[16]; uint4 q[2]; } ph, pl;
#pragma unroll
  for (int oo=0;oo<16;oo++){
    float v = x[(((size_t)b*256 + c0 + oo)<<12) + n];
    u16 h = f2bu(v);
    ph.u[oo] = h; pl.u[oo] = f2bu(v - u2f(h));
  }
  size_t o = (((size_t)b*4096 + n)<<8) + c0;
  *(uint4*)(xh+o) = ph.q[0]; *(uint4*)(xh+o+8) = ph.q[1];
  *(uint4*)(xl+o) = pl.q[0]; *(uint4*)(xl+o+8) = pl.q[1];
}
// bf16 c-major -> bf16 n-major (z1b = transpose of z1h), grid (16,16,8)
__global__ __launch_bounds__(256) void cvt_transpose(const u16* __restrict__ zc,
    u16* __restrict__ zn)
{
  int n  = blockIdx.x*256 + threadIdx.x;
  int c0 = blockIdx.y*16;
  int b  = blockIdx.z;
  union { u16 u[16]; uint4 q[2]; } pk;
#pragma unroll
  for (int oo=0;oo<16;oo++)
    pk.u[oo] = zc[(((size_t)b*256 + c0 + oo)<<12) + n];
  u16* dst = zn + (((size_t)b*4096 + n)<<8) + c0;
  *(uint4*)dst       = pk.q[0];
  *(uint4*)(dst + 8) = pk.q[1];
}

// ============================================================================
// depthwise 3x3 + conv BN + norm BN -> split hi/lo bf16 z1
// ============================================================================
__global__ __launch_bounds__(256) void dw_norm_split(const float* __restrict__ pw,
    u16* __restrict__ zh, u16* __restrict__ zl, const float* __restrict__ dww,
    const float* __restrict__ cbs, const float* __restrict__ cbt,
    const float* __restrict__ ns, const float* __restrict__ nt)
{
  size_t idx = (size_t)blockIdx.x*256 + threadIdx.x;
  int n = (int)(idx & 4095);
  int c = (int)((idx>>12) & 255);
  int h = n>>6, wq = n&63;
  const float* p = pw + (idx - n);
  float acc = 0.f;
  for(int i=0;i<3;i++){
    int hh = h+i-1; if((unsigned)hh >= 64u) continue;
    for(int j=0;j<3;j++){
      int ww = wq+j-1; if((unsigned)ww >= 64u) continue;
      acc += dww[c*9 + i*3 + j] * p[hh*64 + ww];
    }
  }
  float bn = acc*cbs[c] + cbt[c];
  float v  = bn*ns[c] + nt[c];
  u16 hi = f2bu(v);
  zh[idx] = hi; zl[idx] = f2bu(v - u2f(hi));
}

// ============================================================================
// Q/K softplus conv, z1 from hi/lo pair (fp32-equivalent input)
// ============================================================================
DEV void mac16hl(const u16* __restrict__ hb, const u16* __restrict__ lb,
                 const float* __restrict__ wb, float* __restrict__ acc)
{
  for (int k=0;k<256;k+=4){
    float a0 = u2f(hb[(size_t)(k+0)<<12]) + u2f(lb[(size_t)(k+0)<<12]);
    float a1 = u2f(hb[(size_t)(k+1)<<12]) + u2f(lb[(size_t)(k+1)<<12]);
    float a2 = u2f(hb[(size_t)(k+2)<<12]) + u2f(lb[(size_t)(k+2)<<12]);
    float a3 = u2f(hb[(size_t)(k+3)<<12]) + u2f(lb[(size_t)(k+3)<<12]);
#pragma unroll
    for (int oo=0;oo<16;oo++){
      const float* wr = wb + (size_t)oo*256 + k;
      acc[oo] = fmaf(a3,wr[3],fmaf(a2,wr[2],fmaf(a1,wr[1],fmaf(a0,wr[0],acc[oo]))));
    }
  }
}

__global__ __launch_bounds__(256) void qk_tile(const u16* __restrict__ zh,
    const u16* __restrict__ zl, const float* __restrict__ qw,
    const float* __restrict__ kw, float* __restrict__ Qf, float* __restrict__ Kf)
{
  int n  = blockIdx.x*256 + threadIdx.x;
  int y  = blockIdx.y;
  int o0 = (y&1)*16;
  int b  = blockIdx.z;
  const float* w   = (y<2) ? qw : kw;
  float*       out = (y<2) ? Qf : Kf;
  const u16* hb = zh + (((size_t)b*256)<<12) + n;
  const u16* lb = zl + (((size_t)b*256)<<12) + n;
  float acc[16] = {};
  mac16hl(hb, lb, w + (size_t)o0*256, acc);
#pragma unroll
  for (int oo=0;oo<16;oo++){
    float a = acc[oo];
    a = fmaxf(a,0.f) + log1pf(expf(-fabsf(a)));      // softplus
    out[(((size_t)b*32 + o0 + oo)<<12) + n] = a;
  }
}

// ============================================================================
// fp32 SYRK for KV (small) — unchanged
// ============================================================================
DEV int swz(int r, int j){ return r*128 + ((j ^ ((r>>2)&7))<<2); }

__global__ __launch_bounds__(256) void syrk32(const float* __restrict__ Kf,
    const float* __restrict__ V, float* __restrict__ Cp)
{
  int dt = blockIdx.x, ks = blockIdx.y, b = blockIdx.z;
  __shared__ __align__(16) float sa[32*128];
  __shared__ __align__(16) float sb[32*128];
  int tx = threadIdx.x & 15, ty = threadIdx.x >> 4;
  const float* Ab = Kf + (((size_t)b*32)<<12);
  const float* Bb = V  + (((size_t)b*256 + dt*32)<<12);
  float acc[2][2] = {};
  for (int k0 = ks<<10; k0 < (ks<<10)+1024; k0 += 128){
    __syncthreads();
#pragma unroll
    for (int i=0;i<4;i++){
      int fi = threadIdx.x + i*256;
      int r = fi >> 5, j = fi & 31;
      *(float4*)&sa[swz(r,j)] = *(const float4*)&Ab[((size_t)r<<12) + k0 + (j<<2)];
      *(float4*)&sb[swz(r,j)] = *(const float4*)&Bb[((size_t)r<<12) + k0 + (j<<2)];
    }
    __syncthreads();
#pragma unroll 4
    for (int jj=0;jj<32;jj++){
      float4 av[2], bv[2];
#pragma unroll
      for (int i=0;i<2;i++) av[i] = *(const float4*)&sa[swz(2*ty+i,jj)];
#pragma unroll
      for (int i=0;i<2;i++) bv[i] = *(const float4*)&sb[swz(2*tx+i,jj)];
#pragma unroll
      for (int i=0;i<2;i++)
#pragma unroll
        for (int j2=0;j2<2;j2++)
          acc[i][j2] = fmaf(av[i].w,bv[j2].w, fmaf(av[i].z,bv[j2].z,
                       fmaf(av[i].y,bv[j2].y, fmaf(av[i].x,bv[j2].x, acc[i][j2]))));
    }
  }
  float* Cb = Cp + ((size_t)ks*8 + b)*8192;
#pragma unroll
  for (int i=0;i<2;i++)
#pragma unroll
    for (int j2=0;j2<2;j2++)
      Cb[(size_t)(2*ty+i)*256 + dt*32 + 2*tx + j2] = acc[i][j2];
}

__global__ __launch_bounds__(256) void kv_combine(const float* __restrict__ p,
    float* __restrict__ o)
{
  int i = blockIdx.x*256 + threadIdx.x;
  o[i] = p[i] + p[i+65536] + p[i+131072] + p[i+196608];
}

// ---- softmax of (rowmax - e), summing 16 K-split partials; bf16 att out
__global__ __launch_bounds__(256) void softmax16(const float* __restrict__ Ep,
    u16* __restrict__ att)
{
  int bc = blockIdx.x;                 // b*256 + c
  int b = bc>>8, c = bc&255;
  size_t base = (size_t)b*65536 + (size_t)c*256;
  int d = threadIdx.x;
  float ed = 0.f;
#pragma unroll
  for(int ks=0;ks<16;ks++) ed += Ep[base + (size_t)ks*524288 + d];
  __shared__ float red[4];
  int lane = d&63, wid = d>>6;
  float v = ed;
  for (int off=32;off;off>>=1) v = fmaxf(v, __shfl_down(v,off));
  if(lane==0) red[wid]=v;
  __syncthreads();
  float rowmax = fmaxf(fmaxf(red[0],red[1]),fmaxf(red[2],red[3]));
  __syncthreads();
  float s = rowmax - ed;
  float v2 = s;
  for (int off=32;off;off>>=1) v2 = fmaxf(v2, __shfl_down(v2,off));
  if(lane==0) red[wid]=v2;
  __syncthreads();
  float smax = fmaxf(fmaxf(red[0],red[1]),fmaxf(red[2],red[3]));
  __syncthreads();
  float p = expf(s - smax);
  float sv = p;
  for (int off=32;off;off>>=1) sv += __shfl_down(sv,off);
  if(lane==0) red[wid]=sv;
  __syncthreads();
  float sum = red[0]+red[1]+red[2]+red[3];
  att[((size_t)bc<<8)+d] = f2bu(p/sum);
}

// ============================================================================
// light epilogue (z1/other reconstructed from hi/lo), n-major bf16 px out
// ============================================================================
__global__ __launch_bounds__(256) void catt_px(const u16* __restrict__ zh,
    const u16* __restrict__ zl, const u16* __restrict__ oh,
    const u16* __restrict__ ol, const float* __restrict__ Qf,
    const float* __restrict__ KVf, const float* __restrict__ invb,
    const float* __restrict__ s1b, const float* __restrict__ gkp,
    const float* __restrict__ gcp, const float* __restrict__ ns,
    const float* __restrict__ nt, u16* __restrict__ px)
{
  int n  = blockIdx.x*256 + threadIdx.x;
  int c0 = blockIdx.y*16;
  int b  = blockIdx.z;
  const float* qb  = Qf  + (((size_t)b*Mm)<<12) + n;
  const float* kvb = KVf + ((size_t)b<<13) + c0;
  float s2[16] = {};
#pragma unroll
  for (int m=0;m<Mm;m++){
    float qm = qb[(size_t)m<<12];
#pragma unroll
    for (int oo=0;oo<16;oo++) s2[oo] = fmaf(qm, kvb[m*256 + oo], s2[oo]);
  }
  float invv = invb[((size_t)b<<12)+n];
  float gk = gkp[0], gc = gcp[0];
  union { u16 u[16]; uint4 q[2]; } pk;
#pragma unroll
  for (int oo=0;oo<16;oo++){
    int c = c0+oo;
    size_t idx = (((size_t)b*256 + c)<<12) + n;
    float zv = u2f(zh[idx]) + u2f(zl[idx]);
    float ov = u2f(oh[idx]) + u2f(ol[idx]);
    float a = 2.f*zv + gc*s1b[idx] + gk*s2[oo]*invv;
    pk.u[oo] = f2bu(ov*a*ns[c] + nt[c]);
  }
  u16* dst = px + (((size_t)b*4096 + n)<<8) + c0;
  *(uint4*)dst       = pk.q[0];
  *(uint4*)(dst + 8) = pk.q[1];
}

// ============================================================================
// small fp32 kernels (unchanged)
// ============================================================================
__global__ __launch_bounds__(256) void rowsum_lit(const float* __restrict__ A, float* __restrict__ out)
{
  int x = blockIdx.x;
  const float* ar = A + ((size_t)x << 12);
  float a = 0.f;
  for(int n=threadIdx.x; n<Nn; n+=256) a += ar[n];
  __shared__ float red[4];
  for(int off=32;off;off>>=1) a += __shfl_down(a,off);
  int lane = threadIdx.x&63, wid = threadIdx.x>>6;
  if(lane==0) red[wid]=a;
  __syncthreads();
  if(threadIdx.x==0) out[x] = red[0]+red[1]+red[2]+red[3];
}

__global__ __launch_bounds__(256) void inv_lit(const float* __restrict__ Qf,
    const float* __restrict__ Ks, float* __restrict__ invb)
{
  size_t idx = (size_t)blockIdx.x*256 + threadIdx.x;
  int b = (int)(idx>>12);
  const float* qb = Qf + ((size_t)b*Mm << 12) + (int)(idx&4095);
  const float* ks = Ks + b*Mm;
  float s = 0.f;
  for(int m=0;m<Mm;m++) s += qb[(size_t)m<<12]*(ks[m]+EPSc);
  invb[idx] = 1.f/s;
}

__global__ __launch_bounds__(256) void final_y(const float* __restrict__ yin,
    const float* __restrict__ acc, const float* __restrict__ b2,
    const float* __restrict__ s2, const float* __restrict__ t2, float* __restrict__ out)
{
  size_t idx = (size_t)blockIdx.x*256 + threadIdx.x;
  int c = (int)((idx>>12) & 255);
  float y2 = (acc[idx] + b2[c])*s2[c] + t2[c];
  out[ACT + idx] = yin[idx] + y2;
}

__global__ __launch_bounds__(256) void final_x(const float* __restrict__ xin,
    const float* __restrict__ acc, const float* __restrict__ b2,
    const float* __restrict__ s2, const float* __restrict__ t2, float* __restrict__ out)
{
  size_t idx = (size_t)blockIdx.x*256 + threadIdx.x;
  int c = (int)((idx>>12) & 255);
  float x2 = (acc[idx] + b2[c])*s2[c] + t2[c];
  out[idx] = xin[idx] + x2 + out[ACT + idx];
}

extern "C" void kernel_launch(void* const* d_in, const int* in_sizes, int n_in,
                              void* d_out, int out_size, void* d_ws, size_t ws_size,
                              hipStream_t stream)
{
  (void)in_sizes; (void)n_in; (void)out_size; (void)ws_size;
  const float* xin  = (const float*)d_in[0];
  const float* yin  = (const float*)d_in[1];
  const float* pw_w = (const float*)d_in[2];
  const float* dw_w = (const float*)d_in[3];
  const float* cbs  = (const float*)d_in[4];
  const float* cbt  = (const float*)d_in[5];
  const float* ns   = (const float*)d_in[6];
  const float* nt   = (const float*)d_in[7];
  const float* q_w  = (const float*)d_in[8];
  const float* k_w  = (const float*)d_in[9];
  const float* v_w  = (const float*)d_in[10];
  const float* gk   = (const float*)d_in[11];
  const float* gc   = (const float*)d_in[12];
  const float* fc1_w= (const float*)d_in[13];
  const float* fc1_b= (const float*)d_in[14];
  const float* bn1s = (const float*)d_in[15];
  const float* bn1t = (const float*)d_in[16];
  const float* fc2_w= (const float*)d_in[17];
  const float* fc2_b= (const float*)d_in[18];
  const float* bn2s = (const float*)d_in[19];
  const float* bn2t = (const float*)d_in[20];

  char* ws = (char*)d_ws;
  // ---- workspace (same proven 145,097,728-byte footprint) ----
  float* A     = (float*)(ws);                // 0..32M: pw-out / V / Ep(16x2M) / s1 / accb
  u16*   x1h   = (u16*)  (ws + 33554432);     // 32..48M bf16 c-major hi
  u16*   x1l   = (u16*)  (ws + 50331648);     // 48..64M bf16 c-major lo
  u16*   y1h   = (u16*)  (ws + 67108864);     // 64..80M
  u16*   y1l   = (u16*)  (ws + 83886080);     // 80..96M
  u16*   hid   = (u16*)  (ws + 33554432);     // phase3: bf16 [8][4096][1024] = 64M overlay
  u16*   px_y  = (u16*)  (ws + 100663296);    // 96..112M bf16 n-major
  u16*   px_x  = (u16*)  (ws + 117440512);    // 112..128M bf16 n-major
  u16*   xh_nm = (u16*)  (ws + 100663296);    // phase1 transient (over px_y)
  u16*   xl_nm = (u16*)  (ws + 117440512);    // phase1 transient (over px_x)
  u16*   z1b   = (u16*)  (ws + 117440512);    // phase2 transient (over px_x, dead at t=1 end)
  float* Qf    = (float*)(ws + 134217728);    // 128..132M fp32 [8,32,4096]
  float* Kf    = (float*)(ws + 138412032);    // 132..136M
  u16*   pwh   = (u16*)  (ws + 134217728);    // phase1 only (over Qf): 128K
  u16*   pwl   = (u16*)  (ws + 134217728 + 131072); // 128K
  u16*   attb  = (u16*)  (ws + 142606336);    // 136..137M bf16 [8][256][256] = 1M
  u16*   fc1wb = (u16*)  (ws + 142606336);    // phase3 overlay: 512K
  u16*   fc2wb = (u16*)  (ws + 142606336 + 524288); // 512K
  float* KVf   = (float*)(ws + 143654912);    // 256K fp32 [8,32,256]
  float* Ksf   = (float*)(ws + 143917056);    // 1K
  float* invb  = (float*)(ws + 143918080);    // 128K
  float* KVp   = (float*)(ws + 144049152);    // 1M KV partials (per-t)
  u16*   vwb   = (u16*)  (ws + 144049152);    // 128K, re-converted per t (KVp clobbers)
  float* Ep    = A;                           // energy partials 16x2M = 32M (over dead V)
  float* accb  = A;                           // phase3 accumulate

  dim3 blk(256);
  dim3 gPX(16,16,8), gQK(16,4,8), gKV(8,4,8);
  dim3 gPW(32,2,8), gEn(2,2,128), gG256(32,2,8), gFC1(32,8,8), gFC2(32,2,8);

  // ---- Phase 1: z1 = norm(bn(dw3(pw(z)))) via split-bf16 MFMA (fp32-equiv)
  cvt_wsplit<<<dim3(256),blk,0,stream>>>(pw_w, pwh, pwl);
  for (int im=0;im<2;im++){
    const float* in = (im==0) ? xin : yin;
    u16* zh = (im==0) ? x1h : y1h;
    u16* zl = (im==0) ? x1l : y1l;
    cvt_split_nm<<<gPX,blk,0,stream>>>(in, xh_nm, xl_nm);
    gemm3<4,1,0><<<gPW,blk,0,stream>>>(pwh, pwl, 256, 0,
                                       xh_nm, xl_nm, 256, 1048576, A);
    dw_norm_split<<<dim3(32768),blk,0,stream>>>(A, zh, zl, dw_w, cbs, cbt, ns, nt);
  }

  // ---- Phase 2
  for (int t=0;t<2;t++){
    const u16* zh = (t==0) ? x1h : y1h;
    const u16* zl = (t==0) ? x1l : y1l;
    const u16* oh = (t==0) ? y1h : x1h;
    const u16* ol = (t==0) ? y1l : x1l;
    u16* pxout    = (t==0) ? px_y : px_x;
    cvt_w<<<dim3(256),blk,0,stream>>>(v_w, vwb);
    cvt_transpose<<<gPX,blk,0,stream>>>(zh, z1b);
    qk_tile<<<gQK,blk,0,stream>>>(zh, zl, q_w, k_w, Qf, Kf);
    gemm_bf16<256,0><<<gG256,blk,0,stream>>>(vwb, 0, z1b, A, nullptr,
                                             nullptr, nullptr, nullptr);      // V fp32
    syrk32<<<gKV,blk,0,stream>>>(Kf, A, KVp);
    kv_combine<<<dim3(256),blk,0,stream>>>(KVp, KVf);
    rowsum_lit<<<dim3(256),blk,0,stream>>>(Kf, Ksf);
    inv_lit<<<dim3(128),blk,0,stream>>>(Qf, Ksf, invb);
    // energy = z.z^T via split-bf16 (fp32-equivalent), 16-way K-split
    gemm3<4,16,2><<<gEn,blk,0,stream>>>(zh, zl, 4096, 1048576,
                                        zh, zl, 4096, 1048576, Ep);
    softmax16<<<dim3(2048),blk,0,stream>>>(Ep, attb);
    gemm_bf16<256,0><<<gG256,blk,0,stream>>>(attb, 65536, z1b, A, nullptr,
                                             nullptr, nullptr, nullptr);      // s1 fp32
    catt_px<<<gPX,blk,0,stream>>>(zh, zl, oh, ol, Qf, KVf, invb, A,
                                  gk, gc, ns, nt, pxout);
  }

  // ---- Phase 3: MLPs via bf16 MFMA
  cvt_w<<<dim3(1024),blk,0,stream>>>(fc1_w, fc1wb);
  cvt_w<<<dim3(1024),blk,0,stream>>>(fc2_w, fc2wb);
  for (int s=0;s<2;s++){
    const u16* px = (s==0) ? px_y : px_x;
    gemm_bf16<256,1><<<gFC1,blk,0,stream>>>(fc1wb, 0, px, nullptr, hid,
                                            fc1_b, bn1s, bn1t);
    gemm_bf16<1024,0><<<gFC2,blk,0,stream>>>(fc2wb, 0, hid, accb, nullptr,
                                             nullptr, nullptr, nullptr);
    if (s==0) final_y<<<dim3(32768),blk,0,stream>>>(yin, accb, fc2_b, bn2s, bn2t, (float*)d_out);
    else      final_x<<<dim3(32768),blk,0,stream>>>(xin, accb, fc2_b, bn2s, bn2t, (float*)d_out);
  }
}

// Round 4
// 769.047 us; speedup vs baseline: 19.9314x; 1.1257x over previous
//
#include <hip/hip_runtime.h>
#include <hip/hip_bf16.h>
#include <math.h>

typedef __hip_bfloat16 bf16;
typedef unsigned short u16;
#define DEV __device__ __forceinline__

DEV float tofl(float v){ return v; }
DEV bf16  f2b(float v){ return __float2bfloat16(v); }
DEV u16   f2bu(float v){ bf16 h = f2b(v); u16 u; __builtin_memcpy(&u,&h,2); return u; }
DEV float u2f(u16 u){ bf16 h; __builtin_memcpy(&h,&u,2); return __bfloat162float(h); }

static constexpr int Cc=256, Nn=4096, Mm=32;
static constexpr size_t ACT = (size_t)8*Cc*Nn;
static constexpr float EPSc = 1e-6f;

typedef __attribute__((ext_vector_type(8))) __bf16 bf16x8;
typedef __attribute__((ext_vector_type(4))) float  f32x4;

// ============================================================================
// MFMA GEMM building blocks (128x128 tile, BK=64, 4 waves, 16x16x32 bf16,
// XOR-swizzled LDS, double-buffered, load-early/write-late). Proven round 2/3.
// ============================================================================
struct StageRegs { int4 a[4], b[4]; };

DEV void stage_load(const u16* __restrict__ gA, int ldA,
                    const u16* __restrict__ gB, int ldB, int tid, StageRegs& r)
{
  int row = tid>>3, g = tid&7;
#pragma unroll
  for(int i=0;i<4;i++){
    r.a[i] = *(const int4*)(gA + (size_t)(row+32*i)*ldA + g*8);
    r.b[i] = *(const int4*)(gB + (size_t)(row+32*i)*ldB + g*8);
  }
}
DEV void stage_write(u16* __restrict__ sA, u16* __restrict__ sB,
                     int tid, const StageRegs& r)
{
  int row = tid>>3, g = tid&7;
#pragma unroll
  for(int i=0;i<4;i++){
    int rr = row+32*i;
    int gg = ((g ^ (rr&7))<<3);
    *(int4*)(sA + rr*64 + gg) = r.a[i];
    *(int4*)(sB + rr*64 + gg) = r.b[i];
  }
}

// ---- plain bf16 GEMM.
// OMODE 0: fp32 c-major out.  OMODE 1: fc1 bf16 n-major out + relu6 BN.
// OMODE 3: bf16 c-major out.
template<int KDIM, int OMODE>
__global__ __launch_bounds__(256,2) void gemm_bf16(
    const u16* __restrict__ A, long sAb,
    const u16* __restrict__ B,
    float* __restrict__ Cf, u16* __restrict__ Cb,
    const float* __restrict__ bia, const float* __restrict__ scl,
    const float* __restrict__ sht)
{
  __shared__ __align__(16) u16 sA[2][8192];
  __shared__ __align__(16) u16 sB[2][8192];
  int tid = threadIdx.x;
  int nt = blockIdx.x, mt = blockIdx.y, b = blockIdx.z;
  const u16* gA = A + (size_t)b*sAb + (size_t)mt*128*KDIM;
  const u16* gB = B + ((size_t)b*4096 + (size_t)nt*128)*KDIM;
  int w = tid>>6, l = tid&63;
  int wr = w>>1, wc = w&1;
  int l15 = l&15, lg = l>>4;
  f32x4 acc[4][4] = {};
  StageRegs r;
  stage_load(gA, KDIM, gB, KDIM, tid, r);
  stage_write(sA[0], sB[0], tid, r);
  __syncthreads();
  constexpr int NT = KDIM/64;
  for(int t=0;t<NT;t++){
    int cur = t&1;
    if(t+1<NT) stage_load(gA + (t+1)*64, KDIM, gB + (t+1)*64, KDIM, tid, r);
#pragma unroll
    for(int ks=0;ks<2;ks++){
      bf16x8 af[4], bfr[4];
#pragma unroll
      for(int m=0;m<4;m++){
        int row = wr*64 + m*16 + l15;
        int g = ks*4 + lg;
        af[m] = *(const bf16x8*)(&sA[cur][row*64 + ((g^(row&7))<<3)]);
      }
#pragma unroll
      for(int nn=0;nn<4;nn++){
        int row = wc*64 + nn*16 + l15;
        int g = ks*4 + lg;
        bfr[nn] = *(const bf16x8*)(&sB[cur][row*64 + ((g^(row&7))<<3)]);
      }
#pragma unroll
      for(int m=0;m<4;m++)
#pragma unroll
        for(int nn=0;nn<4;nn++)
          acc[m][nn] = __builtin_amdgcn_mfma_f32_16x16x32_bf16(af[m], bfr[nn], acc[m][nn], 0,0,0);
    }
    if(t+1<NT) stage_write(sA[cur^1], sB[cur^1], tid, r);
    __syncthreads();
  }
  int obase = mt*128 + wr*64;
  int nbase = nt*128 + wc*64;
  if (OMODE==0){
    size_t Mrows = (size_t)gridDim.y*128;
#pragma unroll
    for(int m=0;m<4;m++)
#pragma unroll
      for(int nn=0;nn<4;nn++){
        int o_ = obase + m*16 + (lg<<2);
        int n_ = nbase + nn*16 + l15;
        float* dst = Cf + (((size_t)b*Mrows + o_)<<12) + n_;
#pragma unroll
        for(int i=0;i<4;i++) dst[(size_t)i<<12] = acc[m][nn][i];
      }
  } else if (OMODE==1){
#pragma unroll
    for(int m=0;m<4;m++)
#pragma unroll
      for(int nn=0;nn<4;nn++){
        int o_ = obase + m*16 + (lg<<2);
        int n_ = nbase + nn*16 + l15;
        union { u16 u[4]; uint2 v; } pk;
#pragma unroll
        for(int i=0;i<4;i++){
          int o = o_+i;
          float a2 = (acc[m][nn][i] + bia[o])*scl[o] + sht[o];
          pk.u[i] = f2bu(fminf(fmaxf(a2,0.f),6.f));
        }
        *(uint2*)(Cb + ((size_t)b*4096 + (size_t)n_)*1024 + o_) = pk.v;
      }
  } else {   // OMODE 3: bf16 c-major
    size_t Mrows = (size_t)gridDim.y*128;
#pragma unroll
    for(int m=0;m<4;m++)
#pragma unroll
      for(int nn=0;nn<4;nn++){
        int o_ = obase + m*16 + (lg<<2);
        int n_ = nbase + nn*16 + l15;
        u16* dst = Cb + (((size_t)b*Mrows + o_)<<12) + n_;
#pragma unroll
        for(int i=0;i<4;i++) dst[(size_t)i<<12] = f2bu(acc[m][nn][i]);
      }
  }
}

// ---- Q/K fused MFMA conv + softplus. A = [qw(32); kw(32); pad(64)] bf16.
// grid (32,1,8). Writes Qf/Kf fp32 c-major and Kb bf16 c-major.
__global__ __launch_bounds__(256,2) void qk_gemm(
    const u16* __restrict__ Aqk, const u16* __restrict__ B,
    float* __restrict__ Qf, float* __restrict__ Kf, u16* __restrict__ Kb)
{
  __shared__ __align__(16) u16 sA[2][8192];
  __shared__ __align__(16) u16 sB[2][8192];
  int tid = threadIdx.x;
  int nt = blockIdx.x, b = blockIdx.z;
  const u16* gA = Aqk;
  const u16* gB = B + ((size_t)b*4096 + (size_t)nt*128)*256;
  int w = tid>>6, l = tid&63;
  int wr = w>>1, wc = w&1;
  int l15 = l&15, lg = l>>4;
  f32x4 acc[4][4] = {};
  StageRegs r;
  stage_load(gA, 256, gB, 256, tid, r);
  stage_write(sA[0], sB[0], tid, r);
  __syncthreads();
  for(int t=0;t<4;t++){
    int cur = t&1;
    if(t+1<4) stage_load(gA + (t+1)*64, 256, gB + (t+1)*64, 256, tid, r);
#pragma unroll
    for(int ks=0;ks<2;ks++){
      bf16x8 af[4], bfr[4];
#pragma unroll
      for(int m=0;m<4;m++){
        int row = wr*64 + m*16 + l15;
        int g = ks*4 + lg;
        af[m] = *(const bf16x8*)(&sA[cur][row*64 + ((g^(row&7))<<3)]);
      }
#pragma unroll
      for(int nn=0;nn<4;nn++){
        int row = wc*64 + nn*16 + l15;
        int g = ks*4 + lg;
        bfr[nn] = *(const bf16x8*)(&sB[cur][row*64 + ((g^(row&7))<<3)]);
      }
#pragma unroll
      for(int m=0;m<4;m++)
#pragma unroll
        for(int nn=0;nn<4;nn++)
          acc[m][nn] = __builtin_amdgcn_mfma_f32_16x16x32_bf16(af[m], bfr[nn], acc[m][nn], 0,0,0);
    }
    if(t+1<4) stage_write(sA[cur^1], sB[cur^1], tid, r);
    __syncthreads();
  }
  if (wr!=0) return;                       // rows 64-127 are padding
  int nbase = nt*128 + wc*64;
#pragma unroll
  for(int m=0;m<4;m++)
#pragma unroll
    for(int nn=0;nn<4;nn++){
      int o_ = m*16 + (lg<<2);             // 0..63
      int n_ = nbase + nn*16 + l15;
#pragma unroll
      for(int i=0;i<4;i++){
        float a = acc[m][nn][i];
        a = fmaxf(a,0.f) + log1pf(expf(-fabsf(a)));     // softplus
        if (m<2){                                        // Q rows 0..31
          Qf[(((size_t)b*32 + o_+i)<<12) + n_] = a;
        } else {                                         // K rows 32..63
          int kr = o_+i-32;
          Kf[(((size_t)b*32 + kr)<<12) + n_] = a;
          Kb[(((size_t)b*32 + kr)<<12) + n_] = f2bu(a);
        }
      }
    }
}

// ---- KV = K·V^T via MFMA, reduction over contiguous n (c-major operands).
// A rows replicated &31 (K has 32 rows; tile is 128). grid (2,1,8*16).
// Partials Cp[ks][b][32][256] fp32.
__global__ __launch_bounds__(256,2) void kv_gemm(const u16* __restrict__ Kb,
    const u16* __restrict__ Vb, float* __restrict__ Cp)
{
  __shared__ __align__(16) u16 sA[2][8192];
  __shared__ __align__(16) u16 sB[2][8192];
  int tid = threadIdx.x;
  int nt = blockIdx.x;
  int b  = blockIdx.z >> 4, ks = blockIdx.z & 15;
  const u16* gA = Kb + ((size_t)b*32)*4096 + ks*256;
  const u16* gB = Vb + ((size_t)b*256 + (size_t)nt*128)*4096 + ks*256;
  int row = tid>>3, g = tid&7;
  int w = tid>>6, l = tid&63;
  int wr = w>>1, wc = w&1;
  int l15 = l&15, lg = l>>4;
  f32x4 acc[4][4] = {};
  StageRegs r;
  // custom stage: A rows mod 32 (replicate K vertically), B normal
#define KV_LOAD(koff) do { \
    _Pragma("unroll") \
    for(int i=0;i<4;i++){ \
      r.a[i] = *(const int4*)(gA + (size_t)row*4096 + (koff) + g*8); \
      r.b[i] = *(const int4*)(gB + (size_t)(row+32*i)*4096 + (koff) + g*8); \
    } } while(0)
  KV_LOAD(0);
  stage_write(sA[0], sB[0], tid, r);
  __syncthreads();
  for(int t=0;t<4;t++){
    int cur = t&1;
    if(t+1<4) KV_LOAD((t+1)*64);
#pragma unroll
    for(int kss=0;kss<2;kss++){
      bf16x8 af[4], bfr[4];
#pragma unroll
      for(int m=0;m<4;m++){
        int rr = wr*64 + m*16 + l15;
        int gg = kss*4 + lg;
        af[m] = *(const bf16x8*)(&sA[cur][rr*64 + ((gg^(rr&7))<<3)]);
      }
#pragma unroll
      for(int nn=0;nn<4;nn++){
        int rr = wc*64 + nn*16 + l15;
        int gg = kss*4 + lg;
        bfr[nn] = *(const bf16x8*)(&sB[cur][rr*64 + ((gg^(rr&7))<<3)]);
      }
#pragma unroll
      for(int m=0;m<4;m++)
#pragma unroll
        for(int nn=0;nn<4;nn++)
          acc[m][nn] = __builtin_amdgcn_mfma_f32_16x16x32_bf16(af[m], bfr[nn], acc[m][nn], 0,0,0);
    }
    if(t+1<4) stage_write(sA[cur^1], sB[cur^1], tid, r);
    __syncthreads();
  }
#undef KV_LOAD
  if (wr!=0) return;
  float* Cb = Cp + ((size_t)ks*8 + b)*8192;
#pragma unroll
  for(int m=0;m<2;m++)                      // rows 0..31 only (32+ are replicas)
#pragma unroll
    for(int nn=0;nn<4;nn++){
      int o_ = m*16 + (lg<<2);
      int c_ = nt*128 + wc*64 + nn*16 + l15;
#pragma unroll
      for(int i=0;i<4;i++) Cb[(size_t)(o_+i)*256 + c_] = acc[m][nn][i];
    }
}

__global__ __launch_bounds__(256) void kv_combine16(const float* __restrict__ p,
    float* __restrict__ o)
{
  int i = blockIdx.x*256 + threadIdx.x;     // 65536 = 8*32*256
  float s = 0.f;
#pragma unroll
  for(int ks=0;ks<16;ks++) s += p[(size_t)ks*65536 + i];
  o[i] = s;
}

// ---- split-bf16 3-pass GEMM (pw conv + energy) — unchanged from round 3
template<int KTILES, int KSPLIT, int OMODE>
__global__ __launch_bounds__(256,2) void gemm3(
    const u16* __restrict__ Ah, const u16* __restrict__ Al, int ldA, long sAb,
    const u16* __restrict__ Bh, const u16* __restrict__ Bl, int ldB, long sBb,
    float* __restrict__ Cf)
{
  __shared__ __align__(16) u16 sA[2][8192];
  __shared__ __align__(16) u16 sB[2][8192];
  int tid = threadIdx.x;
  int nt = blockIdx.x, mt = blockIdx.y;
  int b  = blockIdx.z / KSPLIT, ks = blockIdx.z % KSPLIT;
  long koff = (long)ks * (KTILES*64);
  const u16* A0 = Ah + (size_t)b*sAb + (size_t)mt*128*ldA + koff;
  const u16* A1 = Al + (size_t)b*sAb + (size_t)mt*128*ldA + koff;
  const u16* B0 = Bh + (size_t)b*sBb + (size_t)nt*128*ldB + koff;
  const u16* B1 = Bl + (size_t)b*sBb + (size_t)nt*128*ldB + koff;
  int w = tid>>6, l = tid&63;
  int wr = w>>1, wc = w&1;
  int l15 = l&15, lg = l>>4;
  f32x4 acc[4][4] = {};
  StageRegs r;
  for(int pass=0; pass<3; ++pass){
    const u16* gA = (pass==2) ? A1 : A0;
    const u16* gB = (pass==1) ? B1 : B0;
    stage_load(gA, ldA, gB, ldB, tid, r);
    stage_write(sA[0], sB[0], tid, r);
    __syncthreads();
    for(int t=0;t<KTILES;t++){
      int cur = t&1;
      if(t+1<KTILES) stage_load(gA + (t+1)*64, ldA, gB + (t+1)*64, ldB, tid, r);
#pragma unroll
      for(int kss=0;kss<2;kss++){
        bf16x8 af[4], bfr[4];
#pragma unroll
        for(int m=0;m<4;m++){
          int row = wr*64 + m*16 + l15;
          int g = kss*4 + lg;
          af[m] = *(const bf16x8*)(&sA[cur][row*64 + ((g^(row&7))<<3)]);
        }
#pragma unroll
        for(int nn=0;nn<4;nn++){
          int row = wc*64 + nn*16 + l15;
          int g = kss*4 + lg;
          bfr[nn] = *(const bf16x8*)(&sB[cur][row*64 + ((g^(row&7))<<3)]);
        }
#pragma unroll
        for(int m=0;m<4;m++)
#pragma unroll
          for(int nn=0;nn<4;nn++)
            acc[m][nn] = __builtin_amdgcn_mfma_f32_16x16x32_bf16(af[m], bfr[nn], acc[m][nn], 0,0,0);
      }
      if(t+1<KTILES) stage_write(sA[cur^1], sB[cur^1], tid, r);
      __syncthreads();
    }
  }
  int obase = mt*128 + wr*64;
  int nbase = nt*128 + wc*64;
  if (OMODE==0){
    size_t Mrows = (size_t)gridDim.y*128;
#pragma unroll
    for(int m=0;m<4;m++)
#pragma unroll
      for(int nn=0;nn<4;nn++){
        int o_ = obase + m*16 + (lg<<2);
        int n_ = nbase + nn*16 + l15;
        float* dst = Cf + (((size_t)b*Mrows + o_)<<12) + n_;
#pragma unroll
        for(int i=0;i<4;i++) dst[(size_t)i<<12] = acc[m][nn][i];
      }
  } else {
    int gridB = gridDim.z / KSPLIT;
    float* Cb = Cf + ((size_t)ks*gridB + b)*65536;
#pragma unroll
    for(int m=0;m<4;m++)
#pragma unroll
      for(int nn=0;nn<4;nn++){
        int o_ = obase + m*16 + (lg<<2);
        int n_ = nbase + nn*16 + l15;
#pragma unroll
        for(int i=0;i<4;i++) Cb[(size_t)(o_+i)*256 + n_] = acc[m][nn][i];
      }
  }
}

// ============================================================================
// conversion kernels
// ============================================================================
__global__ __launch_bounds__(256) void cvt_w(const float* __restrict__ s,
    u16* __restrict__ d)
{
  int i = blockIdx.x*256 + threadIdx.x;
  d[i] = f2bu(s[i]);
}
__global__ __launch_bounds__(256) void cvt_wsplit(const float* __restrict__ s,
    u16* __restrict__ dh, u16* __restrict__ dl)
{
  int i = blockIdx.x*256 + threadIdx.x;
  float v = s[i];
  u16 h = f2bu(v);
  dh[i] = h; dl[i] = f2bu(v - u2f(h));
}
// Aqk = [qw(32); kw(32); zeros(64)] bf16 row-major [128][256]; grid(128)
__global__ __launch_bounds__(256) void cvt_qk(const float* __restrict__ q,
    const float* __restrict__ k, u16* __restrict__ A)
{
  int r = blockIdx.x, c = threadIdx.x;
  float v = 0.f;
  if (r < 32) v = q[r*256 + c];
  else if (r < 64) v = k[(r-32)*256 + c];
  A[r*256 + c] = f2bu(v);
}
// fp32 c-major -> split hi/lo bf16 n-major (pw conv B operand), grid (16,16,8)
__global__ __launch_bounds__(256) void cvt_split_nm(const float* __restrict__ x,
    u16* __restrict__ xh, u16* __restrict__ xl)
{
  int n  = blockIdx.x*256 + threadIdx.x;
  int c0 = blockIdx.y*16;
  int b  = blockIdx.z;
  union { u16 u[16]; uint4 q[2]; } ph, pl;
#pragma unroll
  for (int oo=0;oo<16;oo++){
    float v = x[(((size_t)b*256 + c0 + oo)<<12) + n];
    u16 h = f2bu(v);
    ph.u[oo] = h; pl.u[oo] = f2bu(v - u2f(h));
  }
  size_t o = (((size_t)b*4096 + n)<<8) + c0;
  *(uint4*)(xh+o) = ph.q[0]; *(uint4*)(xh+o+8) = ph.q[1];
  *(uint4*)(xl+o) = pl.q[0]; *(uint4*)(xl+o+8) = pl.q[1];
}
// bf16 c-major -> bf16 n-major, grid (16,16,8)
__global__ __launch_bounds__(256) void cvt_transpose(const u16* __restrict__ zc,
    u16* __restrict__ zn)
{
  int n  = blockIdx.x*256 + threadIdx.x;
  int c0 = blockIdx.y*16;
  int b  = blockIdx.z;
  union { u16 u[16]; uint4 q[2]; } pk;
#pragma unroll
  for (int oo=0;oo<16;oo++)
    pk.u[oo] = zc[(((size_t)b*256 + c0 + oo)<<12) + n];
  u16* dst = zn + (((size_t)b*4096 + n)<<8) + c0;
  *(uint4*)dst       = pk.q[0];
  *(uint4*)(dst + 8) = pk.q[1];
}

// ============================================================================
// depthwise 3x3 + conv BN + norm BN -> split hi/lo bf16 z1
// ============================================================================
__global__ __launch_bounds__(256) void dw_norm_split(const float* __restrict__ pw,
    u16* __restrict__ zh, u16* __restrict__ zl, const float* __restrict__ dww,
    const float* __restrict__ cbs, const float* __restrict__ cbt,
    const float* __restrict__ ns, const float* __restrict__ nt)
{
  size_t idx = (size_t)blockIdx.x*256 + threadIdx.x;
  int n = (int)(idx & 4095);
  int c = (int)((idx>>12) & 255);
  int h = n>>6, wq = n&63;
  const float* p = pw + (idx - n);
  float acc = 0.f;
  for(int i=0;i<3;i++){
    int hh = h+i-1; if((unsigned)hh >= 64u) continue;
    for(int j=0;j<3;j++){
      int ww = wq+j-1; if((unsigned)ww >= 64u) continue;
      acc += dww[c*9 + i*3 + j] * p[hh*64 + ww];
    }
  }
  float bn = acc*cbs[c] + cbt[c];
  float v  = bn*ns[c] + nt[c];
  u16 hi = f2bu(v);
  zh[idx] = hi; zl[idx] = f2bu(v - u2f(hi));
}

// ---- softmax of (rowmax - e), summing 16 K-split partials; bf16 att out
__global__ __launch_bounds__(256) void softmax16(const float* __restrict__ Ep,
    u16* __restrict__ att)
{
  int bc = blockIdx.x;                 // b*256 + c
  int b = bc>>8, c = bc&255;
  size_t base = (size_t)b*65536 + (size_t)c*256;
  int d = threadIdx.x;
  float ed = 0.f;
#pragma unroll
  for(int ks=0;ks<16;ks++) ed += Ep[base + (size_t)ks*524288 + d];
  __shared__ float red[4];
  int lane = d&63, wid = d>>6;
  float v = ed;
  for (int off=32;off;off>>=1) v = fmaxf(v, __shfl_down(v,off));
  if(lane==0) red[wid]=v;
  __syncthreads();
  float rowmax = fmaxf(fmaxf(red[0],red[1]),fmaxf(red[2],red[3]));
  __syncthreads();
  float s = rowmax - ed;
  float v2 = s;
  for (int off=32;off;off>>=1) v2 = fmaxf(v2, __shfl_down(v2,off));
  if(lane==0) red[wid]=v2;
  __syncthreads();
  float smax = fmaxf(fmaxf(red[0],red[1]),fmaxf(red[2],red[3]));
  __syncthreads();
  float p = expf(s - smax);
  float sv = p;
  for (int off=32;off;off>>=1) sv += __shfl_down(sv,off);
  if(lane==0) red[wid]=sv;
  __syncthreads();
  float sum = red[0]+red[1]+red[2]+red[3];
  att[((size_t)bc<<8)+d] = f2bu(p/sum);
}

// ============================================================================
// light epilogue (z1/other from hi/lo; s1 bf16), n-major bf16 px out
// ============================================================================
__global__ __launch_bounds__(256) void catt_px(const u16* __restrict__ zh,
    const u16* __restrict__ zl, const u16* __restrict__ oh,
    const u16* __restrict__ ol, const float* __restrict__ Qf,
    const float* __restrict__ KVf, const float* __restrict__ invb,
    const u16* __restrict__ s1b, const float* __restrict__ gkp,
    const float* __restrict__ gcp, const float* __restrict__ ns,
    const float* __restrict__ nt, u16* __restrict__ px)
{
  int n  = blockIdx.x*256 + threadIdx.x;
  int c0 = blockIdx.y*16;
  int b  = blockIdx.z;
  const float* qb  = Qf  + (((size_t)b*Mm)<<12) + n;
  const float* kvb = KVf + ((size_t)b<<13) + c0;
  float s2[16] = {};
#pragma unroll
  for (int m=0;m<Mm;m++){
    float qm = qb[(size_t)m<<12];
#pragma unroll
    for (int oo=0;oo<16;oo++) s2[oo] = fmaf(qm, kvb[m*256 + oo], s2[oo]);
  }
  float invv = invb[((size_t)b<<12)+n];
  float gk = gkp[0], gc = gcp[0];
  union { u16 u[16]; uint4 q[2]; } pk;
#pragma unroll
  for (int oo=0;oo<16;oo++){
    int c = c0+oo;
    size_t idx = (((size_t)b*256 + c)<<12) + n;
    float zv = u2f(zh[idx]) + u2f(zl[idx]);
    float ov = u2f(oh[idx]) + u2f(ol[idx]);
    float a = 2.f*zv + gc*u2f(s1b[idx]) + gk*s2[oo]*invv;
    pk.u[oo] = f2bu(ov*a*ns[c] + nt[c]);
  }
  u16* dst = px + (((size_t)b*4096 + n)<<8) + c0;
  *(uint4*)dst       = pk.q[0];
  *(uint4*)(dst + 8) = pk.q[1];
}

// ============================================================================
// small fp32 kernels (unchanged)
// ============================================================================
__global__ __launch_bounds__(256) void rowsum_lit(const float* __restrict__ A, float* __restrict__ out)
{
  int x = blockIdx.x;
  const float* ar = A + ((size_t)x << 12);
  float a = 0.f;
  for(int n=threadIdx.x; n<Nn; n+=256) a += ar[n];
  __shared__ float red[4];
  for(int off=32;off;off>>=1) a += __shfl_down(a,off);
  int lane = threadIdx.x&63, wid = threadIdx.x>>6;
  if(lane==0) red[wid]=a;
  __syncthreads();
  if(threadIdx.x==0) out[x] = red[0]+red[1]+red[2]+red[3];
}

__global__ __launch_bounds__(256) void inv_lit(const float* __restrict__ Qf,
    const float* __restrict__ Ks, float* __restrict__ invb)
{
  size_t idx = (size_t)blockIdx.x*256 + threadIdx.x;
  int b = (int)(idx>>12);
  const float* qb = Qf + ((size_t)b*Mm << 12) + (int)(idx&4095);
  const float* ks = Ks + b*Mm;
  float s = 0.f;
  for(int m=0;m<Mm;m++) s += qb[(size_t)m<<12]*(ks[m]+EPSc);
  invb[idx] = 1.f/s;
}

__global__ __launch_bounds__(256) void final_y(const float* __restrict__ yin,
    const float* __restrict__ acc, const float* __restrict__ b2,
    const float* __restrict__ s2, const float* __restrict__ t2, float* __restrict__ out)
{
  size_t idx = (size_t)blockIdx.x*256 + threadIdx.x;
  int c = (int)((idx>>12) & 255);
  float y2 = (acc[idx] + b2[c])*s2[c] + t2[c];
  out[ACT + idx] = yin[idx] + y2;
}

__global__ __launch_bounds__(256) void final_x(const float* __restrict__ xin,
    const float* __restrict__ acc, const float* __restrict__ b2,
    const float* __restrict__ s2, const float* __restrict__ t2, float* __restrict__ out)
{
  size_t idx = (size_t)blockIdx.x*256 + threadIdx.x;
  int c = (int)((idx>>12) & 255);
  float x2 = (acc[idx] + b2[c])*s2[c] + t2[c];
  out[idx] = xin[idx] + x2 + out[ACT + idx];
}

extern "C" void kernel_launch(void* const* d_in, const int* in_sizes, int n_in,
                              void* d_out, int out_size, void* d_ws, size_t ws_size,
                              hipStream_t stream)
{
  (void)in_sizes; (void)n_in; (void)out_size; (void)ws_size;
  const float* xin  = (const float*)d_in[0];
  const float* yin  = (const float*)d_in[1];
  const float* pw_w = (const float*)d_in[2];
  const float* dw_w = (const float*)d_in[3];
  const float* cbs  = (const float*)d_in[4];
  const float* cbt  = (const float*)d_in[5];
  const float* ns   = (const float*)d_in[6];
  const float* nt   = (const float*)d_in[7];
  const float* q_w  = (const float*)d_in[8];
  const float* k_w  = (const float*)d_in[9];
  const float* v_w  = (const float*)d_in[10];
  const float* gk   = (const float*)d_in[11];
  const float* gc   = (const float*)d_in[12];
  const float* fc1_w= (const float*)d_in[13];
  const float* fc1_b= (const float*)d_in[14];
  const float* bn1s = (const float*)d_in[15];
  const float* bn1t = (const float*)d_in[16];
  const float* fc2_w= (const float*)d_in[17];
  const float* fc2_b= (const float*)d_in[18];
  const float* bn2s = (const float*)d_in[19];
  const float* bn2t = (const float*)d_in[20];

  char* ws = (char*)d_ws;
  // ---- workspace (same proven 145,097,728-byte footprint) ----
  // A region (0..32M) time-multiplex per t:
  //   [Vb bf16 16M @0][KV partials 4M @16M][Kb bf16 2M @20M] -> then
  //   [Ep 32M @0] -> [s1b16 bf16 16M @0] -> phase3 accb fp32 32M @0
  u16*   Vb    = (u16*)  (ws);
  float* KVp   = (float*)(ws + 16777216);
  u16*   Kb    = (u16*)  (ws + 20971520);
  float* Ep    = (float*)(ws);
  u16*   s1b16 = (u16*)  (ws);
  float* accb  = (float*)(ws);
  float* Apw   = (float*)(ws);                // phase1 pw output (fp32 32M)
  u16*   x1h   = (u16*)  (ws + 33554432);     // 32..48M bf16 c-major hi
  u16*   x1l   = (u16*)  (ws + 50331648);     // 48..64M lo
  u16*   y1h   = (u16*)  (ws + 67108864);     // 64..80M
  u16*   y1l   = (u16*)  (ws + 83886080);     // 80..96M
  u16*   hid   = (u16*)  (ws + 33554432);     // phase3 overlay: 64M
  u16*   px_y  = (u16*)  (ws + 100663296);    // 96..112M bf16 n-major
  u16*   px_x  = (u16*)  (ws + 117440512);    // 112..128M bf16 n-major
  u16*   xh_nm = (u16*)  (ws + 100663296);    // phase1 transient (over px_y)
  u16*   xl_nm = (u16*)  (ws + 117440512);    // phase1 transient (over px_x)
  u16*   z1b   = (u16*)  (ws + 117440512);    // phase2 transient (over px_x)
  float* Qf    = (float*)(ws + 134217728);    // 128..132M fp32 [8,32,4096]
  float* Kf    = (float*)(ws + 138412032);    // 132..136M
  u16*   pwh   = (u16*)  (ws + 134217728);    // phase1 only (over Qf): 128K
  u16*   pwl   = (u16*)  (ws + 134217728 + 131072);
  u16*   attb  = (u16*)  (ws + 142606336);    // 136..137M bf16 [8][256][256]
  u16*   fc1wb = (u16*)  (ws + 142606336);    // phase3 overlay: 512K
  u16*   fc2wb = (u16*)  (ws + 142606336 + 524288);
  float* KVf   = (float*)(ws + 143654912);    // 256K fp32 [8,32,256]
  float* Ksf   = (float*)(ws + 143917056);    // 1K
  float* invb  = (float*)(ws + 143918080);    // 128K
  u16*   vwb   = (u16*)  (ws + 144049152);    // 128K (stable now)
  u16*   Aqk   = (u16*)  (ws + 144049152 + 131072); // 64K stable
  // end of Aqk = 144,245,760 < 145,097,728 ✓

  dim3 blk(256);
  dim3 gPX(16,16,8);
  dim3 gPW(32,2,8), gEn(2,2,128), gG256(32,2,8), gQKg(32,1,8), gKVg(2,1,128);
  dim3 gFC1(32,8,8), gFC2(32,2,8);

  // ---- static weight conversions (stable slots)
  cvt_w<<<dim3(256),blk,0,stream>>>(v_w, vwb);
  cvt_qk<<<dim3(128),blk,0,stream>>>(q_w, k_w, Aqk);

  // ---- Phase 1: z1 = norm(bn(dw3(pw(z)))) via split-bf16 MFMA (fp32-equiv)
  cvt_wsplit<<<dim3(256),blk,0,stream>>>(pw_w, pwh, pwl);
  for (int im=0;im<2;im++){
    const float* in = (im==0) ? xin : yin;
    u16* zh = (im==0) ? x1h : y1h;
    u16* zl = (im==0) ? x1l : y1l;
    cvt_split_nm<<<gPX,blk,0,stream>>>(in, xh_nm, xl_nm);
    gemm3<4,1,0><<<gPW,blk,0,stream>>>(pwh, pwl, 256, 0,
                                       xh_nm, xl_nm, 256, 1048576, Apw);
    dw_norm_split<<<dim3(32768),blk,0,stream>>>(Apw, zh, zl, dw_w, cbs, cbt, ns, nt);
  }

  // ---- Phase 2
  for (int t=0;t<2;t++){
    const u16* zh = (t==0) ? x1h : y1h;
    const u16* zl = (t==0) ? x1l : y1l;
    const u16* oh = (t==0) ? y1h : x1h;
    const u16* ol = (t==0) ? y1l : x1l;
    u16* pxout    = (t==0) ? px_y : px_x;
    cvt_transpose<<<gPX,blk,0,stream>>>(zh, z1b);
    qk_gemm<<<gQKg,blk,0,stream>>>(Aqk, z1b, Qf, Kf, Kb);
    gemm_bf16<256,3><<<gG256,blk,0,stream>>>(vwb, 0, z1b, nullptr, Vb,
                                             nullptr, nullptr, nullptr);      // V bf16
    kv_gemm<<<gKVg,blk,0,stream>>>(Kb, Vb, KVp);
    kv_combine16<<<dim3(256),blk,0,stream>>>(KVp, KVf);
    rowsum_lit<<<dim3(256),blk,0,stream>>>(Kf, Ksf);
    inv_lit<<<dim3(128),blk,0,stream>>>(Qf, Ksf, invb);
    // energy = z.z^T via split-bf16 (fp32-equivalent), 16-way K-split
    gemm3<4,16,2><<<gEn,blk,0,stream>>>(zh, zl, 4096, 1048576,
                                        zh, zl, 4096, 1048576, Ep);
    softmax16<<<dim3(2048),blk,0,stream>>>(Ep, attb);
    gemm_bf16<256,3><<<gG256,blk,0,stream>>>(attb, 65536, z1b, nullptr, s1b16,
                                             nullptr, nullptr, nullptr);      // s1 bf16
    catt_px<<<gPX,blk,0,stream>>>(zh, zl, oh, ol, Qf, KVf, invb, s1b16,
                                  gk, gc, ns, nt, pxout);
  }

  // ---- Phase 3: MLPs via bf16 MFMA
  cvt_w<<<dim3(1024),blk,0,stream>>>(fc1_w, fc1wb);
  cvt_w<<<dim3(1024),blk,0,stream>>>(fc2_w, fc2wb);
  for (int s=0;s<2;s++){
    const u16* px = (s==0) ? px_y : px_x;
    gemm_bf16<256,1><<<gFC1,blk,0,stream>>>(fc1wb, 0, px, nullptr, hid,
                                            fc1_b, bn1s, bn1t);
    gemm_bf16<1024,0><<<gFC2,blk,0,stream>>>(fc2wb, 0, hid, accb, nullptr,
                                             nullptr, nullptr, nullptr);
    if (s==0) final_y<<<dim3(32768),blk,0,stream>>>(yin, accb, fc2_b, bn2s, bn2t, (float*)d_out);
    else      final_x<<<dim3(32768),blk,0,stream>>>(xin, accb, fc2_b, bn2s, bn2t, (float*)d_out);
  }
}

// Round 5
// 693.338 us; speedup vs baseline: 22.1078x; 1.1092x over previous
//
#include <hip/hip_runtime.h>
#include <hip/hip_bf16.h>
#include <math.h>

typedef __hip_bfloat16 bf16;
typedef unsigned short u16;
#define DEV __device__ __forceinline__

DEV float tofl(float v){ return v; }
DEV bf16  f2b(float v){ return __float2bfloat16(v); }
DEV u16   f2bu(float v){ bf16 h = f2b(v); u16 u; __builtin_memcpy(&u,&h,2); return u; }
DEV float u2f(u16 u){ bf16 h; __builtin_memcpy(&h,&u,2); return __bfloat162float(h); }

static constexpr int Cc=256, Nn=4096, Mm=32;
static constexpr size_t ACT = (size_t)8*Cc*Nn;
static constexpr float EPSc = 1e-6f;

typedef __attribute__((ext_vector_type(8))) __bf16 bf16x8;
typedef __attribute__((ext_vector_type(4))) float  f32x4;

// ============================================================================
// MFMA GEMM building blocks (128x128 tile, BK=64, 4 waves, 16x16x32 bf16,
// XOR-swizzled LDS, double-buffered, load-early/write-late). Proven round 2/3.
// ============================================================================
struct StageRegs { int4 a[4], b[4]; };

DEV void stage_load(const u16* __restrict__ gA, int ldA,
                    const u16* __restrict__ gB, int ldB, int tid, StageRegs& r)
{
  int row = tid>>3, g = tid&7;
#pragma unroll
  for(int i=0;i<4;i++){
    r.a[i] = *(const int4*)(gA + (size_t)(row+32*i)*ldA + g*8);
    r.b[i] = *(const int4*)(gB + (size_t)(row+32*i)*ldB + g*8);
  }
}
DEV void stage_write(u16* __restrict__ sA, u16* __restrict__ sB,
                     int tid, const StageRegs& r)
{
  int row = tid>>3, g = tid&7;
#pragma unroll
  for(int i=0;i<4;i++){
    int rr = row+32*i;
    int gg = ((g ^ (rr&7))<<3);
    *(int4*)(sA + rr*64 + gg) = r.a[i];
    *(int4*)(sB + rr*64 + gg) = r.b[i];
  }
}

// ---- plain bf16 GEMM.
// OMODE 0: fp32 c-major out.  OMODE 1: fc1 bf16 n-major out + relu6 BN.
// OMODE 3: bf16 c-major out.
template<int KDIM, int OMODE>
__global__ __launch_bounds__(256,2) void gemm_bf16(
    const u16* __restrict__ A, long sAb,
    const u16* __restrict__ B,
    float* __restrict__ Cf, u16* __restrict__ Cb,
    const float* __restrict__ bia, const float* __restrict__ scl,
    const float* __restrict__ sht)
{
  __shared__ __align__(16) u16 sA[2][8192];
  __shared__ __align__(16) u16 sB[2][8192];
  int tid = threadIdx.x;
  int nt = blockIdx.x, mt = blockIdx.y, b = blockIdx.z;
  const u16* gA = A + (size_t)b*sAb + (size_t)mt*128*KDIM;
  const u16* gB = B + ((size_t)b*4096 + (size_t)nt*128)*KDIM;
  int w = tid>>6, l = tid&63;
  int wr = w>>1, wc = w&1;
  int l15 = l&15, lg = l>>4;
  f32x4 acc[4][4] = {};
  StageRegs r;
  stage_load(gA, KDIM, gB, KDIM, tid, r);
  stage_write(sA[0], sB[0], tid, r);
  __syncthreads();
  constexpr int NT = KDIM/64;
  for(int t=0;t<NT;t++){
    int cur = t&1;
    if(t+1<NT) stage_load(gA + (t+1)*64, KDIM, gB + (t+1)*64, KDIM, tid, r);
#pragma unroll
    for(int ks=0;ks<2;ks++){
      bf16x8 af[4], bfr[4];
#pragma unroll
      for(int m=0;m<4;m++){
        int row = wr*64 + m*16 + l15;
        int g = ks*4 + lg;
        af[m] = *(const bf16x8*)(&sA[cur][row*64 + ((g^(row&7))<<3)]);
      }
#pragma unroll
      for(int nn=0;nn<4;nn++){
        int row = wc*64 + nn*16 + l15;
        int g = ks*4 + lg;
        bfr[nn] = *(const bf16x8*)(&sB[cur][row*64 + ((g^(row&7))<<3)]);
      }
#pragma unroll
      for(int m=0;m<4;m++)
#pragma unroll
        for(int nn=0;nn<4;nn++)
          acc[m][nn] = __builtin_amdgcn_mfma_f32_16x16x32_bf16(af[m], bfr[nn], acc[m][nn], 0,0,0);
    }
    if(t+1<NT) stage_write(sA[cur^1], sB[cur^1], tid, r);
    __syncthreads();
  }
  int obase = mt*128 + wr*64;
  int nbase = nt*128 + wc*64;
  if (OMODE==0){
    size_t Mrows = (size_t)gridDim.y*128;
#pragma unroll
    for(int m=0;m<4;m++)
#pragma unroll
      for(int nn=0;nn<4;nn++){
        int o_ = obase + m*16 + (lg<<2);
        int n_ = nbase + nn*16 + l15;
        float* dst = Cf + (((size_t)b*Mrows + o_)<<12) + n_;
#pragma unroll
        for(int i=0;i<4;i++) dst[(size_t)i<<12] = acc[m][nn][i];
      }
  } else if (OMODE==1){
#pragma unroll
    for(int m=0;m<4;m++)
#pragma unroll
      for(int nn=0;nn<4;nn++){
        int o_ = obase + m*16 + (lg<<2);
        int n_ = nbase + nn*16 + l15;
        union { u16 u[4]; uint2 v; } pk;
#pragma unroll
        for(int i=0;i<4;i++){
          int o = o_+i;
          float a2 = (acc[m][nn][i] + bia[o])*scl[o] + sht[o];
          pk.u[i] = f2bu(fminf(fmaxf(a2,0.f),6.f));
        }
        *(uint2*)(Cb + ((size_t)b*4096 + (size_t)n_)*1024 + o_) = pk.v;
      }
  } else {   // OMODE 3: bf16 c-major
    size_t Mrows = (size_t)gridDim.y*128;
#pragma unroll
    for(int m=0;m<4;m++)
#pragma unroll
      for(int nn=0;nn<4;nn++){
        int o_ = obase + m*16 + (lg<<2);
        int n_ = nbase + nn*16 + l15;
        u16* dst = Cb + (((size_t)b*Mrows + o_)<<12) + n_;
#pragma unroll
        for(int i=0;i<4;i++) dst[(size_t)i<<12] = f2bu(acc[m][nn][i]);
      }
  }
}

// ---- Q/K fused MFMA conv + softplus. A = [qw(32); kw(32); pad(64)] bf16.
// grid (32,1,8). Writes Qf/Kf fp32 c-major and Kb bf16 c-major.
__global__ __launch_bounds__(256,2) void qk_gemm(
    const u16* __restrict__ Aqk, const u16* __restrict__ B,
    float* __restrict__ Qf, float* __restrict__ Kf, u16* __restrict__ Kb)
{
  __shared__ __align__(16) u16 sA[2][8192];
  __shared__ __align__(16) u16 sB[2][8192];
  int tid = threadIdx.x;
  int nt = blockIdx.x, b = blockIdx.z;
  const u16* gA = Aqk;
  const u16* gB = B + ((size_t)b*4096 + (size_t)nt*128)*256;
  int w = tid>>6, l = tid&63;
  int wr = w>>1, wc = w&1;
  int l15 = l&15, lg = l>>4;
  f32x4 acc[4][4] = {};
  StageRegs r;
  stage_load(gA, 256, gB, 256, tid, r);
  stage_write(sA[0], sB[0], tid, r);
  __syncthreads();
  for(int t=0;t<4;t++){
    int cur = t&1;
    if(t+1<4) stage_load(gA + (t+1)*64, 256, gB + (t+1)*64, 256, tid, r);
#pragma unroll
    for(int ks=0;ks<2;ks++){
      bf16x8 af[4], bfr[4];
#pragma unroll
      for(int m=0;m<4;m++){
        int row = wr*64 + m*16 + l15;
        int g = ks*4 + lg;
        af[m] = *(const bf16x8*)(&sA[cur][row*64 + ((g^(row&7))<<3)]);
      }
#pragma unroll
      for(int nn=0;nn<4;nn++){
        int row = wc*64 + nn*16 + l15;
        int g = ks*4 + lg;
        bfr[nn] = *(const bf16x8*)(&sB[cur][row*64 + ((g^(row&7))<<3)]);
      }
#pragma unroll
      for(int m=0;m<4;m++)
#pragma unroll
        for(int nn=0;nn<4;nn++)
          acc[m][nn] = __builtin_amdgcn_mfma_f32_16x16x32_bf16(af[m], bfr[nn], acc[m][nn], 0,0,0);
    }
    if(t+1<4) stage_write(sA[cur^1], sB[cur^1], tid, r);
    __syncthreads();
  }
  if (wr!=0) return;                       // rows 64-127 are padding
  int nbase = nt*128 + wc*64;
#pragma unroll
  for(int m=0;m<4;m++)
#pragma unroll
    for(int nn=0;nn<4;nn++){
      int o_ = m*16 + (lg<<2);             // 0..63
      int n_ = nbase + nn*16 + l15;
#pragma unroll
      for(int i=0;i<4;i++){
        float a = acc[m][nn][i];
        a = fmaxf(a,0.f) + log1pf(expf(-fabsf(a)));     // softplus
        if (m<2){                                        // Q rows 0..31
          Qf[(((size_t)b*32 + o_+i)<<12) + n_] = a;
        } else {                                         // K rows 32..63
          int kr = o_+i-32;
          Kf[(((size_t)b*32 + kr)<<12) + n_] = a;
          Kb[(((size_t)b*32 + kr)<<12) + n_] = f2bu(a);
        }
      }
    }
}

// ---- KV = K·V^T via MFMA, reduction over contiguous n (c-major operands).
// A rows replicated &31 (K has 32 rows; tile is 128). grid (2,1,8*16).
// Partials Cp[ks][b][32][256] fp32.
__global__ __launch_bounds__(256,2) void kv_gemm(const u16* __restrict__ Kb,
    const u16* __restrict__ Vb, float* __restrict__ Cp)
{
  __shared__ __align__(16) u16 sA[2][8192];
  __shared__ __align__(16) u16 sB[2][8192];
  int tid = threadIdx.x;
  int nt = blockIdx.x;
  int b  = blockIdx.z >> 4, ks = blockIdx.z & 15;
  const u16* gA = Kb + ((size_t)b*32)*4096 + ks*256;
  const u16* gB = Vb + ((size_t)b*256 + (size_t)nt*128)*4096 + ks*256;
  int row = tid>>3, g = tid&7;
  int w = tid>>6, l = tid&63;
  int wr = w>>1, wc = w&1;
  int l15 = l&15, lg = l>>4;
  f32x4 acc[4][4] = {};
  StageRegs r;
  // custom stage: A rows mod 32 (replicate K vertically), B normal
#define KV_LOAD(koff) do { \
    _Pragma("unroll") \
    for(int i=0;i<4;i++){ \
      r.a[i] = *(const int4*)(gA + (size_t)row*4096 + (koff) + g*8); \
      r.b[i] = *(const int4*)(gB + (size_t)(row+32*i)*4096 + (koff) + g*8); \
    } } while(0)
  KV_LOAD(0);
  stage_write(sA[0], sB[0], tid, r);
  __syncthreads();
  for(int t=0;t<4;t++){
    int cur = t&1;
    if(t+1<4) KV_LOAD((t+1)*64);
#pragma unroll
    for(int kss=0;kss<2;kss++){
      bf16x8 af[4], bfr[4];
#pragma unroll
      for(int m=0;m<4;m++){
        int rr = wr*64 + m*16 + l15;
        int gg = kss*4 + lg;
        af[m] = *(const bf16x8*)(&sA[cur][rr*64 + ((gg^(rr&7))<<3)]);
      }
#pragma unroll
      for(int nn=0;nn<4;nn++){
        int rr = wc*64 + nn*16 + l15;
        int gg = kss*4 + lg;
        bfr[nn] = *(const bf16x8*)(&sB[cur][rr*64 + ((gg^(rr&7))<<3)]);
      }
#pragma unroll
      for(int m=0;m<4;m++)
#pragma unroll
        for(int nn=0;nn<4;nn++)
          acc[m][nn] = __builtin_amdgcn_mfma_f32_16x16x32_bf16(af[m], bfr[nn], acc[m][nn], 0,0,0);
    }
    if(t+1<4) stage_write(sA[cur^1], sB[cur^1], tid, r);
    __syncthreads();
  }
#undef KV_LOAD
  if (wr!=0) return;
  float* Cb = Cp + ((size_t)ks*8 + b)*8192;
#pragma unroll
  for(int m=0;m<2;m++)                      // rows 0..31 only (32+ are replicas)
#pragma unroll
    for(int nn=0;nn<4;nn++){
      int o_ = m*16 + (lg<<2);
      int c_ = nt*128 + wc*64 + nn*16 + l15;
#pragma unroll
      for(int i=0;i<4;i++) Cb[(size_t)(o_+i)*256 + c_] = acc[m][nn][i];
    }
}

__global__ __launch_bounds__(256) void kv_combine16(const float* __restrict__ p,
    float* __restrict__ o)
{
  int i = blockIdx.x*256 + threadIdx.x;     // 65536 = 8*32*256
  float s = 0.f;
#pragma unroll
  for(int ks=0;ks<16;ks++) s += p[(size_t)ks*65536 + i];
  o[i] = s;
}

// ---- split-bf16 3-pass GEMM (pw conv + energy) — unchanged from round 3
template<int KTILES, int KSPLIT, int OMODE>
__global__ __launch_bounds__(256,2) void gemm3(
    const u16* __restrict__ Ah, const u16* __restrict__ Al, int ldA, long sAb,
    const u16* __restrict__ Bh, const u16* __restrict__ Bl, int ldB, long sBb,
    float* __restrict__ Cf)
{
  __shared__ __align__(16) u16 sA[2][8192];
  __shared__ __align__(16) u16 sB[2][8192];
  int tid = threadIdx.x;
  int nt = blockIdx.x, mt = blockIdx.y;
  int b  = blockIdx.z / KSPLIT, ks = blockIdx.z % KSPLIT;
  long koff = (long)ks * (KTILES*64);
  const u16* A0 = Ah + (size_t)b*sAb + (size_t)mt*128*ldA + koff;
  const u16* A1 = Al + (size_t)b*sAb + (size_t)mt*128*ldA + koff;
  const u16* B0 = Bh + (size_t)b*sBb + (size_t)nt*128*ldB + koff;
  const u16* B1 = Bl + (size_t)b*sBb + (size_t)nt*128*ldB + koff;
  int w = tid>>6, l = tid&63;
  int wr = w>>1, wc = w&1;
  int l15 = l&15, lg = l>>4;
  f32x4 acc[4][4] = {};
  StageRegs r;
  for(int pass=0; pass<3; ++pass){
    const u16* gA = (pass==2) ? A1 : A0;
    const u16* gB = (pass==1) ? B1 : B0;
    stage_load(gA, ldA, gB, ldB, tid, r);
    stage_write(sA[0], sB[0], tid, r);
    __syncthreads();
    for(int t=0;t<KTILES;t++){
      int cur = t&1;
      if(t+1<KTILES) stage_load(gA + (t+1)*64, ldA, gB + (t+1)*64, ldB, tid, r);
#pragma unroll
      for(int kss=0;kss<2;kss++){
        bf16x8 af[4], bfr[4];
#pragma unroll
        for(int m=0;m<4;m++){
          int row = wr*64 + m*16 + l15;
          int g = kss*4 + lg;
          af[m] = *(const bf16x8*)(&sA[cur][row*64 + ((g^(row&7))<<3)]);
        }
#pragma unroll
        for(int nn=0;nn<4;nn++){
          int row = wc*64 + nn*16 + l15;
          int g = kss*4 + lg;
          bfr[nn] = *(const bf16x8*)(&sB[cur][row*64 + ((g^(row&7))<<3)]);
        }
#pragma unroll
        for(int m=0;m<4;m++)
#pragma unroll
          for(int nn=0;nn<4;nn++)
            acc[m][nn] = __builtin_amdgcn_mfma_f32_16x16x32_bf16(af[m], bfr[nn], acc[m][nn], 0,0,0);
      }
      if(t+1<KTILES) stage_write(sA[cur^1], sB[cur^1], tid, r);
      __syncthreads();
    }
  }
  int obase = mt*128 + wr*64;
  int nbase = nt*128 + wc*64;
  if (OMODE==0){
    size_t Mrows = (size_t)gridDim.y*128;
#pragma unroll
    for(int m=0;m<4;m++)
#pragma unroll
      for(int nn=0;nn<4;nn++){
        int o_ = obase + m*16 + (lg<<2);
        int n_ = nbase + nn*16 + l15;
        float* dst = Cf + (((size_t)b*Mrows + o_)<<12) + n_;
#pragma unroll
        for(int i=0;i<4;i++) dst[(size_t)i<<12] = acc[m][nn][i];
      }
  } else {
    int gridB = gridDim.z / KSPLIT;
    float* Cb = Cf + ((size_t)ks*gridB + b)*65536;
#pragma unroll
    for(int m=0;m<4;m++)
#pragma unroll
      for(int nn=0;nn<4;nn++){
        int o_ = obase + m*16 + (lg<<2);
        int n_ = nbase + nn*16 + l15;
#pragma unroll
        for(int i=0;i<4;i++) Cb[(size_t)(o_+i)*256 + n_] = acc[m][nn][i];
      }
  }
}

// ============================================================================
// conversion kernels
// ============================================================================
__global__ __launch_bounds__(256) void cvt_w(const float* __restrict__ s,
    u16* __restrict__ d)
{
  int i = blockIdx.x*256 + threadIdx.x;
  d[i] = f2bu(s[i]);
}
__global__ __launch_bounds__(256) void cvt_wsplit(const float* __restrict__ s,
    u16* __restrict__ dh, u16* __restrict__ dl)
{
  int i = blockIdx.x*256 + threadIdx.x;
  float v = s[i];
  u16 h = f2bu(v);
  dh[i] = h; dl[i] = f2bu(v - u2f(h));
}
// Aqk = [qw(32); kw(32); zeros(64)] bf16 row-major [128][256]; grid(128)
__global__ __launch_bounds__(256) void cvt_qk(const float* __restrict__ q,
    const float* __restrict__ k, u16* __restrict__ A)
{
  int r = blockIdx.x, c = threadIdx.x;
  float v = 0.f;
  if (r < 32) v = q[r*256 + c];
  else if (r < 64) v = k[(r-32)*256 + c];
  A[r*256 + c] = f2bu(v);
}
// fp32 c-major -> split hi/lo bf16 n-major (pw conv B operand), grid (16,16,8)
__global__ __launch_bounds__(256) void cvt_split_nm(const float* __restrict__ x,
    u16* __restrict__ xh, u16* __restrict__ xl)
{
  int n  = blockIdx.x*256 + threadIdx.x;
  int c0 = blockIdx.y*16;
  int b  = blockIdx.z;
  union { u16 u[16]; uint4 q[2]; } ph, pl;
#pragma unroll
  for (int oo=0;oo<16;oo++){
    float v = x[(((size_t)b*256 + c0 + oo)<<12) + n];
    u16 h = f2bu(v);
    ph.u[oo] = h; pl.u[oo] = f2bu(v - u2f(h));
  }
  size_t o = (((size_t)b*4096 + n)<<8) + c0;
  *(uint4*)(xh+o) = ph.q[0]; *(uint4*)(xh+o+8) = ph.q[1];
  *(uint4*)(xl+o) = pl.q[0]; *(uint4*)(xl+o+8) = pl.q[1];
}
// bf16 c-major -> bf16 n-major, grid (16,16,8)
__global__ __launch_bounds__(256) void cvt_transpose(const u16* __restrict__ zc,
    u16* __restrict__ zn)
{
  int n  = blockIdx.x*256 + threadIdx.x;
  int c0 = blockIdx.y*16;
  int b  = blockIdx.z;
  union { u16 u[16]; uint4 q[2]; } pk;
#pragma unroll
  for (int oo=0;oo<16;oo++)
    pk.u[oo] = zc[(((size_t)b*256 + c0 + oo)<<12) + n];
  u16* dst = zn + (((size_t)b*4096 + n)<<8) + c0;
  *(uint4*)dst       = pk.q[0];
  *(uint4*)(dst + 8) = pk.q[1];
}

// ============================================================================
// depthwise 3x3 + conv BN + norm BN -> split hi/lo bf16 z1.
// LDS-tiled: one block per (b,c) plane; 66x66 zero-halo tile; 16 px/thread;
// 2-way max bank aliasing (free); uint4 coalesced writes.  [round 5]
// ============================================================================
__global__ __launch_bounds__(256) void dw_norm_tile(const float* __restrict__ pw,
    u16* __restrict__ zh, u16* __restrict__ zl, const float* __restrict__ dww,
    const float* __restrict__ cbs, const float* __restrict__ cbt,
    const float* __restrict__ ns, const float* __restrict__ nt)
{
  int bc = blockIdx.x;                    // b*256 + c
  int c = bc & 255;
  __shared__ float sp[66*66];
  int tid = threadIdx.x;
  // zero halo (disjoint thread ranges; interior written below before sync)
  if (tid < 66){ sp[tid] = 0.f; sp[65*66 + tid] = 0.f; }
  if (tid >= 128 && tid < 192) sp[(tid-128+1)*66] = 0.f;
  if (tid >= 192)              sp[(tid-192+1)*66 + 65] = 0.f;
  // stage the 64x64 fp32 plane (float4-coalesced)
  const float* src = pw + ((size_t)bc << 12);
#pragma unroll
  for(int it=0; it<4; it++){
    int idx = tid + it*256;               // float4 index 0..1023
    int r = idx >> 4, c4 = idx & 15;
    float4 v = *(const float4*)(src + (idx<<2));
    float* d = &sp[(r+1)*66 + 1 + (c4<<2)];
    d[0]=v.x; d[1]=v.y; d[2]=v.z; d[3]=v.w;
  }
  __syncthreads();
  // block-uniform weights & folded BN
  const float* wp = dww + c*9;
  float w00=wp[0], w01=wp[1], w02=wp[2],
        w10=wp[3], w11=wp[4], w12=wp[5],
        w20=wp[6], w21=wp[7], w22=wp[8];
  float sc = cbs[c]*ns[c];
  float sh = cbt[c]*ns[c] + nt[c];
  int r  = tid >> 2;                      // output row 0..63
  int c0 = (tid & 3) << 4;                // output col base 0,16,32,48
  const float* row0 = &sp[r*66 + c0];     // image row r-1, col c0-1 at [0]
  const float* row1 = row0 + 66;
  const float* row2 = row1 + 66;
  union { u16 u[16]; uint4 q[2]; } ph, pl;
#pragma unroll
  for(int j=0;j<16;j++){
    float acc = w00*row0[j] + w01*row0[j+1] + w02*row0[j+2]
              + w10*row1[j] + w11*row1[j+1] + w12*row1[j+2]
              + w20*row2[j] + w21*row2[j+1] + w22*row2[j+2];
    float v = acc*sc + sh;
    u16 hi = f2bu(v);
    ph.u[j] = hi; pl.u[j] = f2bu(v - u2f(hi));
  }
  size_t o = ((size_t)bc << 12) + (r<<6) + c0;
  *(uint4*)(zh+o)   = ph.q[0]; *(uint4*)(zh+o+8) = ph.q[1];
  *(uint4*)(zl+o)   = pl.q[0]; *(uint4*)(zl+o+8) = pl.q[1];
}

// ---- softmax of (rowmax - e), summing 16 K-split partials; bf16 att out
__global__ __launch_bounds__(256) void softmax16(const float* __restrict__ Ep,
    u16* __restrict__ att)
{
  int bc = blockIdx.x;                 // b*256 + c
  int b = bc>>8, c = bc&255;
  size_t base = (size_t)b*65536 + (size_t)c*256;
  int d = threadIdx.x;
  float ed = 0.f;
#pragma unroll
  for(int ks=0;ks<16;ks++) ed += Ep[base + (size_t)ks*524288 + d];
  __shared__ float red[4];
  int lane = d&63, wid = d>>6;
  float v = ed;
  for (int off=32;off;off>>=1) v = fmaxf(v, __shfl_down(v,off));
  if(lane==0) red[wid]=v;
  __syncthreads();
  float rowmax = fmaxf(fmaxf(red[0],red[1]),fmaxf(red[2],red[3]));
  __syncthreads();
  float s = rowmax - ed;
  float v2 = s;
  for (int off=32;off;off>>=1) v2 = fmaxf(v2, __shfl_down(v2,off));
  if(lane==0) red[wid]=v2;
  __syncthreads();
  float smax = fmaxf(fmaxf(red[0],red[1]),fmaxf(red[2],red[3]));
  __syncthreads();
  float p = expf(s - smax);
  float sv = p;
  for (int off=32;off;off>>=1) sv += __shfl_down(sv,off);
  if(lane==0) red[wid]=sv;
  __syncthreads();
  float sum = red[0]+red[1]+red[2]+red[3];
  att[((size_t)bc<<8)+d] = f2bu(p/sum);
}

// ============================================================================
// light epilogue (z1/other from hi/lo; s1 bf16), n-major bf16 px out
// ============================================================================
__global__ __launch_bounds__(256) void catt_px(const u16* __restrict__ zh,
    const u16* __restrict__ zl, const u16* __restrict__ oh,
    const u16* __restrict__ ol, const float* __restrict__ Qf,
    const float* __restrict__ KVf, const float* __restrict__ invb,
    const u16* __restrict__ s1b, const float* __restrict__ gkp,
    const float* __restrict__ gcp, const float* __restrict__ ns,
    const float* __restrict__ nt, u16* __restrict__ px)
{
  int n  = blockIdx.x*256 + threadIdx.x;
  int c0 = blockIdx.y*16;
  int b  = blockIdx.z;
  const float* qb  = Qf  + (((size_t)b*Mm)<<12) + n;
  const float* kvb = KVf + ((size_t)b<<13) + c0;
  float s2[16] = {};
#pragma unroll
  for (int m=0;m<Mm;m++){
    float qm = qb[(size_t)m<<12];
#pragma unroll
    for (int oo=0;oo<16;oo++) s2[oo] = fmaf(qm, kvb[m*256 + oo], s2[oo]);
  }
  float invv = invb[((size_t)b<<12)+n];
  float gk = gkp[0], gc = gcp[0];
  union { u16 u[16]; uint4 q[2]; } pk;
#pragma unroll
  for (int oo=0;oo<16;oo++){
    int c = c0+oo;
    size_t idx = (((size_t)b*256 + c)<<12) + n;
    float zv = u2f(zh[idx]) + u2f(zl[idx]);
    float ov = u2f(oh[idx]) + u2f(ol[idx]);
    float a = 2.f*zv + gc*u2f(s1b[idx]) + gk*s2[oo]*invv;
    pk.u[oo] = f2bu(ov*a*ns[c] + nt[c]);
  }
  u16* dst = px + (((size_t)b*4096 + n)<<8) + c0;
  *(uint4*)dst       = pk.q[0];
  *(uint4*)(dst + 8) = pk.q[1];
}

// ============================================================================
// small fp32 kernels (unchanged)
// ============================================================================
__global__ __launch_bounds__(256) void rowsum_lit(const float* __restrict__ A, float* __restrict__ out)
{
  int x = blockIdx.x;
  const float* ar = A + ((size_t)x << 12);
  float a = 0.f;
  for(int n=threadIdx.x; n<Nn; n+=256) a += ar[n];
  __shared__ float red[4];
  for(int off=32;off;off>>=1) a += __shfl_down(a,off);
  int lane = threadIdx.x&63, wid = threadIdx.x>>6;
  if(lane==0) red[wid]=a;
  __syncthreads();
  if(threadIdx.x==0) out[x] = red[0]+red[1]+red[2]+red[3];
}

__global__ __launch_bounds__(256) void inv_lit(const float* __restrict__ Qf,
    const float* __restrict__ Ks, float* __restrict__ invb)
{
  size_t idx = (size_t)blockIdx.x*256 + threadIdx.x;
  int b = (int)(idx>>12);
  const float* qb = Qf + ((size_t)b*Mm << 12) + (int)(idx&4095);
  const float* ks = Ks + b*Mm;
  float s = 0.f;
  for(int m=0;m<Mm;m++) s += qb[(size_t)m<<12]*(ks[m]+EPSc);
  invb[idx] = 1.f/s;
}

__global__ __launch_bounds__(256) void final_y(const float* __restrict__ yin,
    const float* __restrict__ acc, const float* __restrict__ b2,
    const float* __restrict__ s2, const float* __restrict__ t2, float* __restrict__ out)
{
  size_t idx = (size_t)blockIdx.x*256 + threadIdx.x;
  int c = (int)((idx>>12) & 255);
  float y2 = (acc[idx] + b2[c])*s2[c] + t2[c];
  out[ACT + idx] = yin[idx] + y2;
}

__global__ __launch_bounds__(256) void final_x(const float* __restrict__ xin,
    const float* __restrict__ acc, const float* __restrict__ b2,
    const float* __restrict__ s2, const float* __restrict__ t2, float* __restrict__ out)
{
  size_t idx = (size_t)blockIdx.x*256 + threadIdx.x;
  int c = (int)((idx>>12) & 255);
  float x2 = (acc[idx] + b2[c])*s2[c] + t2[c];
  out[idx] = xin[idx] + x2 + out[ACT + idx];
}

extern "C" void kernel_launch(void* const* d_in, const int* in_sizes, int n_in,
                              void* d_out, int out_size, void* d_ws, size_t ws_size,
                              hipStream_t stream)
{
  (void)in_sizes; (void)n_in; (void)out_size; (void)ws_size;
  const float* xin  = (const float*)d_in[0];
  const float* yin  = (const float*)d_in[1];
  const float* pw_w = (const float*)d_in[2];
  const float* dw_w = (const float*)d_in[3];
  const float* cbs  = (const float*)d_in[4];
  const float* cbt  = (const float*)d_in[5];
  const float* ns   = (const float*)d_in[6];
  const float* nt   = (const float*)d_in[7];
  const float* q_w  = (const float*)d_in[8];
  const float* k_w  = (const float*)d_in[9];
  const float* v_w  = (const float*)d_in[10];
  const float* gk   = (const float*)d_in[11];
  const float* gc   = (const float*)d_in[12];
  const float* fc1_w= (const float*)d_in[13];
  const float* fc1_b= (const float*)d_in[14];
  const float* bn1s = (const float*)d_in[15];
  const float* bn1t = (const float*)d_in[16];
  const float* fc2_w= (const float*)d_in[17];
  const float* fc2_b= (const float*)d_in[18];
  const float* bn2s = (const float*)d_in[19];
  const float* bn2t = (const float*)d_in[20];

  char* ws = (char*)d_ws;
  // ---- workspace (same proven 145,097,728-byte footprint) ----
  u16*   Vb    = (u16*)  (ws);
  float* KVp   = (float*)(ws + 16777216);
  u16*   Kb    = (u16*)  (ws + 20971520);
  float* Ep    = (float*)(ws);
  u16*   s1b16 = (u16*)  (ws);
  float* accb  = (float*)(ws);
  float* Apw   = (float*)(ws);                // phase1 pw output (fp32 32M)
  u16*   x1h   = (u16*)  (ws + 33554432);     // 32..48M bf16 c-major hi
  u16*   x1l   = (u16*)  (ws + 50331648);     // 48..64M lo
  u16*   y1h   = (u16*)  (ws + 67108864);     // 64..80M
  u16*   y1l   = (u16*)  (ws + 83886080);     // 80..96M
  u16*   hid   = (u16*)  (ws + 33554432);     // phase3 overlay: 64M
  u16*   px_y  = (u16*)  (ws + 100663296);    // 96..112M bf16 n-major
  u16*   px_x  = (u16*)  (ws + 117440512);    // 112..128M bf16 n-major
  u16*   xh_nm = (u16*)  (ws + 100663296);    // phase1 transient (over px_y)
  u16*   xl_nm = (u16*)  (ws + 117440512);    // phase1 transient (over px_x)
  u16*   z1b   = (u16*)  (ws + 117440512);    // phase2 transient (over px_x)
  float* Qf    = (float*)(ws + 134217728);    // 128..132M fp32 [8,32,4096]
  float* Kf    = (float*)(ws + 138412032);    // 132..136M
  u16*   pwh   = (u16*)  (ws + 134217728);    // phase1 only (over Qf): 128K
  u16*   pwl   = (u16*)  (ws + 134217728 + 131072);
  u16*   attb  = (u16*)  (ws + 142606336);    // 136..137M bf16 [8][256][256]
  u16*   fc1wb = (u16*)  (ws + 142606336);    // phase3 overlay: 512K
  u16*   fc2wb = (u16*)  (ws + 142606336 + 524288);
  float* KVf   = (float*)(ws + 143654912);    // 256K fp32 [8,32,256]
  float* Ksf   = (float*)(ws + 143917056);    // 1K
  float* invb  = (float*)(ws + 143918080);    // 128K
  u16*   vwb   = (u16*)  (ws + 144049152);    // 128K (stable)
  u16*   Aqk   = (u16*)  (ws + 144049152 + 131072); // 64K stable

  dim3 blk(256);
  dim3 gPX(16,16,8);
  dim3 gPW(32,2,8), gEn(2,2,128), gG256(32,2,8), gQKg(32,1,8), gKVg(2,1,128);
  dim3 gFC1(32,8,8), gFC2(32,2,8);

  // ---- static weight conversions (stable slots)
  cvt_w<<<dim3(256),blk,0,stream>>>(v_w, vwb);
  cvt_qk<<<dim3(128),blk,0,stream>>>(q_w, k_w, Aqk);

  // ---- Phase 1: z1 = norm(bn(dw3(pw(z)))) via split-bf16 MFMA (fp32-equiv)
  cvt_wsplit<<<dim3(256),blk,0,stream>>>(pw_w, pwh, pwl);
  for (int im=0;im<2;im++){
    const float* in = (im==0) ? xin : yin;
    u16* zh = (im==0) ? x1h : y1h;
    u16* zl = (im==0) ? x1l : y1l;
    cvt_split_nm<<<gPX,blk,0,stream>>>(in, xh_nm, xl_nm);
    gemm3<4,1,0><<<gPW,blk,0,stream>>>(pwh, pwl, 256, 0,
                                       xh_nm, xl_nm, 256, 1048576, Apw);
    dw_norm_tile<<<dim3(2048),blk,0,stream>>>(Apw, zh, zl, dw_w, cbs, cbt, ns, nt);
  }

  // ---- Phase 2
  for (int t=0;t<2;t++){
    const u16* zh = (t==0) ? x1h : y1h;
    const u16* zl = (t==0) ? x1l : y1l;
    const u16* oh = (t==0) ? y1h : x1h;
    const u16* ol = (t==0) ? y1l : x1l;
    u16* pxout    = (t==0) ? px_y : px_x;
    cvt_transpose<<<gPX,blk,0,stream>>>(zh, z1b);
    qk_gemm<<<gQKg,blk,0,stream>>>(Aqk, z1b, Qf, Kf, Kb);
    gemm_bf16<256,3><<<gG256,blk,0,stream>>>(vwb, 0, z1b, nullptr, Vb,
                                             nullptr, nullptr, nullptr);      // V bf16
    kv_gemm<<<gKVg,blk,0,stream>>>(Kb, Vb, KVp);
    kv_combine16<<<dim3(256),blk,0,stream>>>(KVp, KVf);
    rowsum_lit<<<dim3(256),blk,0,stream>>>(Kf, Ksf);
    inv_lit<<<dim3(128),blk,0,stream>>>(Qf, Ksf, invb);
    // energy = z.z^T via split-bf16 (fp32-equivalent), 16-way K-split
    gemm3<4,16,2><<<gEn,blk,0,stream>>>(zh, zl, 4096, 1048576,
                                        zh, zl, 4096, 1048576, Ep);
    softmax16<<<dim3(2048),blk,0,stream>>>(Ep, attb);
    gemm_bf16<256,3><<<gG256,blk,0,stream>>>(attb, 65536, z1b, nullptr, s1b16,
                                             nullptr, nullptr, nullptr);      // s1 bf16
    catt_px<<<gPX,blk,0,stream>>>(zh, zl, oh, ol, Qf, KVf, invb, s1b16,
                                  gk, gc, ns, nt, pxout);
  }

  // ---- Phase 3: MLPs via bf16 MFMA
  cvt_w<<<dim3(1024),blk,0,stream>>>(fc1_w, fc1wb);
  cvt_w<<<dim3(1024),blk,0,stream>>>(fc2_w, fc2wb);
  for (int s=0;s<2;s++){
    const u16* px = (s==0) ? px_y : px_x;
    gemm_bf16<256,1><<<gFC1,blk,0,stream>>>(fc1wb, 0, px, nullptr, hid,
                                            fc1_b, bn1s, bn1t);
    gemm_bf16<1024,0><<<gFC2,blk,0,stream>>>(fc2wb, 0, hid, accb, nullptr,
                                             nullptr, nullptr, nullptr);
    if (s==0) final_y<<<dim3(32768),blk,0,stream>>>(yin, accb, fc2_b, bn2s, bn2t, (float*)d_out);
    else      final_x<<<dim3(32768),blk,0,stream>>>(xin, accb, fc2_b, bn2s, bn2t, (float*)d_out);
  }
}